// Round 9
// baseline (1241.814 us; speedup 1.0000x reference)
//
#include <hip/hip_runtime.h>
#include <math.h>

typedef unsigned short u16;
typedef unsigned int u32;
typedef __attribute__((ext_vector_type(8))) short bf16x8;
typedef __attribute__((ext_vector_type(4))) float f32x4;

#define DEV __device__ __forceinline__

DEV float gelu_f(float x) { return 0.5f * x * (1.0f + erff(x * 0.70710678118654752f)); }

DEV float bf2f(u16 b) {
  u32 u = ((u32)b) << 16;
  return __builtin_bit_cast(float, u);
}
DEV u16 f2bf(float f) {
  u32 u = __builtin_bit_cast(u32, f);
  u32 r = (u + 0x7fffu + ((u >> 16) & 1u)) >> 16;
  return (u16)r;
}
DEV u32 pack2(float a, float b) { return (u32)f2bf(a) | ((u32)f2bf(b) << 16); }

DEV void gload16(const u16* g, u16* l) {
  __builtin_amdgcn_global_load_lds(
      (const __attribute__((address_space(1))) void*)g,
      (__attribute__((address_space(3))) void*)l, 16, 0, 0);
}

DEV float dot8(const float* __restrict__ q, uint4 v) {
  float s;
  s = q[0] * bf2f((u16)(v.x & 0xffffu));
  s = fmaf(q[1], bf2f((u16)(v.x >> 16)), s);
  s = fmaf(q[2], bf2f((u16)(v.y & 0xffffu)), s);
  s = fmaf(q[3], bf2f((u16)(v.y >> 16)), s);
  s = fmaf(q[4], bf2f((u16)(v.z & 0xffffu)), s);
  s = fmaf(q[5], bf2f((u16)(v.z >> 16)), s);
  s = fmaf(q[6], bf2f((u16)(v.w & 0xffffu)), s);
  s = fmaf(q[7], bf2f((u16)(v.w >> 16)), s);
  return s;
}

// ================= conv1: direct (CIN=1, k3), NHWC bf16 out =================
__global__ __launch_bounds__(256)
void conv1_k(const float* __restrict__ x, const float* __restrict__ w,
             const float* __restrict__ cbv, const float* __restrict__ gam,
             const float* __restrict__ bet, const float* __restrict__ mu,
             const float* __restrict__ var, u16* __restrict__ out) {
  const int t = blockIdx.x * 256 + threadIdx.x;
  const int fo = blockIdx.y;   // 64
  const int b = blockIdx.z;    // 8
  float xin[3][3];
#pragma unroll
  for (int kh = 0; kh < 3; ++kh) {
    const int fi = 2 * fo + kh - 1;
#pragma unroll
    for (int kw = 0; kw < 3; ++kw) {
      const int tt = t + kw - 1;
      xin[kh][kw] = ((unsigned)fi < 128u && (unsigned)tt < 1024u)
                        ? x[(size_t)(b * 128 + fi) * 1024 + tt] : 0.f;
    }
  }
  u16* dst = out + (((size_t)b * 64 + fo) * 1024 + t) * 32;
#pragma unroll
  for (int g = 0; g < 4; ++g) {
    float vals[8];
#pragma unroll
    for (int cc = 0; cc < 8; ++cc) {
      const int co = g * 8 + cc;
      float acc = 0.f;
#pragma unroll
      for (int kh = 0; kh < 3; ++kh)
#pragma unroll
        for (int kw = 0; kw < 3; ++kw)
          acc = fmaf(xin[kh][kw], w[co * 9 + kh * 3 + kw], acc);
      const float sc = gam[co] * rsqrtf(var[co] + 1e-5f);
      const float sh = (cbv[co] - mu[co]) * sc + bet[co];
      vals[cc] = gelu_f(acc * sc + sh);
    }
    uint4 v;
    v.x = pack2(vals[0], vals[1]); v.y = pack2(vals[2], vals[3]);
    v.z = pack2(vals[4], vals[5]); v.w = pack2(vals[6], vals[7]);
    *(uint4*)(dst + g * 8) = v;
  }
}

// ======= fused weight prep: transposes + conv weight prep + PE table + zpad =======
__global__ __launch_bounds__(256)
void prep_all(const float* __restrict__ proj_w, const float* __restrict__ w_in,
              const float* __restrict__ w_out, const float* __restrict__ w1,
              const float* __restrict__ w2,
              const float* __restrict__ cw2, const float* __restrict__ g2,
              const float* __restrict__ v2,
              const float* __restrict__ cw3, const float* __restrict__ g3,
              const float* __restrict__ v3,
              const float* __restrict__ cw4, const float* __restrict__ g4,
              const float* __restrict__ v4,
              u16* __restrict__ projT, u16* __restrict__ winT,
              u16* __restrict__ woutT, u16* __restrict__ w1T,
              u16* __restrict__ w2T, u16* __restrict__ wp2,
              u16* __restrict__ wp3, u16* __restrict__ wp4,
              float* __restrict__ pe, u16* __restrict__ zpad) {
  __shared__ float tile[32][33];
  const int bid = blockIdx.x, tid = threadIdx.x;
  if (bid == 13608) { if (tid < 128) zpad[tid] = 0; return; }
  const float* src = nullptr; u16* dst = nullptr;
  int K = 0, N = 0, t = 0;
  if (bid < 512) { src = proj_w; dst = projT; K = 1024; N = 512; t = bid; }
  else if (bid < 2048) {
    const int l = bid - 512, i = l / 768; t = l % 768;
    K = 512; N = 1536;
    src = w_in + (size_t)i * 512 * 1536; dst = winT + (size_t)i * 1536 * 512;
  } else if (bid < 2560) {
    const int l = bid - 2048, i = l / 256; t = l % 256;
    K = 512; N = 512;
    src = w_out + (size_t)i * 512 * 512; dst = woutT + (size_t)i * 512 * 512;
  } else if (bid < 4608) {
    const int l = bid - 2560, i = l / 1024; t = l % 1024;
    K = 512; N = 2048;
    src = w1 + (size_t)i * 512 * 2048; dst = w1T + (size_t)i * 2048 * 512;
  } else if (bid < 6656) {
    const int l = bid - 4608, i = l / 1024; t = l % 1024;
    K = 2048; N = 512;
    src = w2 + (size_t)i * 2048 * 512; dst = w2T + (size_t)i * 512 * 2048;
  }
  if (dst) {
    const int ntn = N >> 5;
    const int n0 = (t % ntn) * 32, k0 = (t / ntn) * 32;
    const int tx = tid & 31, ty = tid >> 5;
#pragma unroll
    for (int i = 0; i < 32; i += 8)
      tile[ty + i][tx] = src[(size_t)(k0 + ty + i) * N + n0 + tx];
    __syncthreads();
#pragma unroll
    for (int i = 0; i < 32; i += 8)
      dst[(size_t)(n0 + ty + i) * K + k0 + tx] = f2bf(tile[tx][ty + i]);
    return;
  }
  const float* w = nullptr; const float* gam = nullptr; const float* var = nullptr;
  u16* wp = nullptr; int COUT = 0, CIN = 0, Kk = 0, total = 0, idx = 0;
  if (bid < 6856) { w = cw2; gam = g2; var = v2; wp = wp2; COUT = 64; CIN = 32; Kk = 5; total = 51200; idx = (bid - 6656) * 256 + tid; }
  else if (bid < 8424) { w = cw3; gam = g3; var = v3; wp = wp3; COUT = 128; CIN = 64; Kk = 7; total = 401408; idx = (bid - 6856) * 256 + tid; }
  else if (bid < 11560) { w = cw4; gam = g4; var = v4; wp = wp4; COUT = 128; CIN = 128; Kk = 7; total = 802816; idx = (bid - 8424) * 256 + tid; }
  if (wp) {
    if (idx >= total) return;
    const int KB32 = CIN / 32;
    const int i = idx & 31;
    const int co = (idx >> 5) % COUT;
    const int rest = idx / (32 * COUT);
    const int kw = rest % Kk;
    const int kbh = rest / Kk;
    const int kb = kbh % KB32;
    const int kh = kbh / KB32;
    const int ci = kb * 32 + i;
    const float sc = gam[co] * rsqrtf(var[co] + 1e-5f);
    wp[idx] = f2bf(w[((size_t)(co * CIN + ci) * Kk + kh) * Kk + kw] * sc);
    return;
  }
  const int i = (bid - 11560) * 256 + tid;   // < 1024*512
  const int tt = i >> 9, d = i & 511;
  const float div = expf((float)(d & ~1) * (-0.017988946039015984f));
  const float ang = (float)tt * div;
  pe[i] = (d & 1) ? cosf(ang) : sinf(ang);
}

// ========== implicit-GEMM MFMA conv (NHWC), global_load_lds + swizzled LDS ==========
// WCO=1: each wave computes all COUT (NI = COUT/16) for its own 64 t-rows.
// Staging: direct-to-LDS DMA with pre-swizzled per-lane global source (OOB -> zpad).
template<int CIN, int FIN, int FOUT, int COUT, int K, int PAD, int CHUNK,
         int WT, int WCO, int OUTMODE>
__global__ __launch_bounds__(WT * WCO * 64)
void conv_mfma(const u16* __restrict__ in, const u16* __restrict__ wp,
               const float* __restrict__ cbv, const float* __restrict__ gam,
               const float* __restrict__ bet, const float* __restrict__ mu,
               const float* __restrict__ var, const u16* __restrict__ zpad,
               u16* __restrict__ out) {
  constexpr int NT = WT * WCO * 64, TT = WT * 64;
  constexpr int NI = COUT / (WCO * 16);
  constexpr int XROWS = TT + 16;
  constexpr int KB32 = CIN / 32, NCB = CIN / CHUNK, KS = CHUNK / 32;
  constexpr int SEGS = CHUNK / 8, SMASK = SEGS - 1;
  constexpr int UNITS = XROWS * SEGS;      // multiple of 64
  constexpr int WISS = UNITS / 64;         // wave-issues per chunk
  constexpr int NW = NT / 64;
  __shared__ u16 Xs[2][XROWS * CHUNK];
  const int ttiles = 1024 / TT;
  const int tt = blockIdx.x % ttiles, fo = blockIdx.x / ttiles;
  const int b = blockIdx.y;
  const int t0 = tt * TT;
  const int tid = threadIdx.x, lane = tid & 63;
  const int wave = tid >> 6;
  const int wt = wave % WT, wco = wave / WT;
  const int lc = lane & 15, lg = lane >> 4;
  const int khlo = max(0, PAD - 2 * fo);
  const int khhi = min(K, FIN + PAD - 2 * fo);
  const int nc = (khhi - khlo) * NCB;

  f32x4 acc[4][NI];
#pragma unroll
  for (int mi = 0; mi < 4; ++mi)
#pragma unroll
    for (int ni = 0; ni < NI; ++ni)
#pragma unroll
      for (int j = 0; j < 4; ++j) acc[mi][ni][j] = 0.f;

  // stage chunk c into Xs[buf] via global_load_lds (linear LDS dest,
  // source seg pre-swizzled so LDS ends up in the swizzled layout)
  auto stage = [&](int c, int buf) {
    const int kh = khlo + c / NCB;
    const int fi = 2 * fo + kh - PAD;
    const int cb0 = (c % NCB) * CHUNK;
    const u16* src = in + ((size_t)(b * FIN + fi) * 1024) * CIN + cb0;
#pragma unroll
    for (int iw = wave; iw < WISS; iw += NW) {
      const int u = iw * 64 + lane;
      const int r = u / SEGS, sw = u % SEGS;
      const int seg = sw ^ (r & SMASK);
      const int tg = t0 - 8 + r;
      const u16* g = ((unsigned)tg < 1024u)
                         ? src + (size_t)tg * CIN + seg * 8 : zpad;
      gload16(g, &Xs[buf][(size_t)iw * 64 * 8]);
    }
  };

  stage(0, 0);
  int cur = 0;
  for (int c = 0; c < nc; ++c) {
    __syncthreads();                       // drains vmcnt(0): buf `cur` ready
    if (c + 1 < nc) stage(c + 1, cur ^ 1);
    const int kh = khlo + c / NCB;
    const int cbk = (c % NCB) * KS;
    const u16* xb = &Xs[cur][0];
#pragma unroll
    for (int kw = 0; kw < K; ++kw) {
#pragma unroll
      for (int ks = 0; ks < KS; ++ks) {
        const int kb32 = kh * KB32 + cbk + ks;
        bf16x8 bfr[NI];
#pragma unroll
        for (int ni = 0; ni < NI; ++ni)
          bfr[ni] = *(const bf16x8*)(wp +
              (((size_t)(kb32 * K + kw) * COUT) + (wco * (NI * 16) + ni * 16 + lc)) * 32 + lg * 8);
        bf16x8 afr[4];
#pragma unroll
        for (int mi = 0; mi < 4; ++mi) {
          const int r = wt * 64 + mi * 16 + lc + kw + (8 - PAD);
          const int sw = (ks * 4 + lg) ^ (r & SMASK);
          afr[mi] = *(const bf16x8*)(xb + r * CHUNK + sw * 8);
        }
#pragma unroll
        for (int mi = 0; mi < 4; ++mi)
#pragma unroll
          for (int ni = 0; ni < NI; ++ni)
            acc[mi][ni] = __builtin_amdgcn_mfma_f32_16x16x32_bf16(
                afr[mi], bfr[ni], acc[mi][ni], 0, 0, 0);
      }
    }
    cur ^= 1;
  }
#pragma unroll
  for (int ni = 0; ni < NI; ++ni) {
    const int co = wco * (NI * 16) + ni * 16 + lc;
    const float sc = gam[co] * rsqrtf(var[co] + 1e-5f);
    const float sh = (cbv[co] - mu[co]) * sc + bet[co];
#pragma unroll
    for (int mi = 0; mi < 4; ++mi) {
#pragma unroll
      for (int j = 0; j < 4; ++j) {
        const int tg = t0 + wt * 64 + mi * 16 + lg * 4 + j;
        const float v = gelu_f(acc[mi][ni][j] + sh);
        size_t off;
        if (OUTMODE == 0)
          off = (((size_t)b * FOUT + fo) * 1024 + tg) * COUT + co;
        else
          off = ((size_t)b * 1024 + tg) * 1024 + (size_t)co * 8 + fo;
        out[off] = f2bf(v);
      }
    }
  }
}

// ======= bf16 MFMA GEMM, 128x128 tile, BK=64, XOR-swizzled LDS, XCD-chunked grid ==
template<int EPI, int MT>
__global__ __launch_bounds__(256)
void gemm_bf16(const u16* __restrict__ A, const u16* __restrict__ Bt,
               const float* __restrict__ bias, const float* __restrict__ res,
               void* __restrict__ Cv, int M, int N, int K, int ntn) {
  constexpr int WN = (MT == 128) ? 2 : 4;
  constexpr int NI = 128 / (WN * 16);
  constexpr int AITER = MT / 32;
  __shared__ u16 As[2][MT * 64];
  __shared__ u16 Bs[2][128 * 64];
  const int nwg = gridDim.x;
  const int q8 = nwg >> 3;
  const int idx = (blockIdx.x & 7) * q8 + (blockIdx.x >> 3);
  const int n0 = (idx % ntn) * 128, m0 = (idx / ntn) * MT;
  const int tid = threadIdx.x, lane = tid & 63, wave = tid >> 6;
  const int wm = wave / WN, wn = wave % WN;
  const int lc = lane & 15, lg = lane >> 4;
  const int srow = tid >> 3, sseg = tid & 7;
  f32x4 acc[4][NI];
#pragma unroll
  for (int mi = 0; mi < 4; ++mi)
#pragma unroll
    for (int ni = 0; ni < NI; ++ni)
#pragma unroll
      for (int j = 0; j < 4; ++j) acc[mi][ni][j] = 0.f;

  uint4 ra[AITER], rb[4];
  auto load_ch = [&](int kc) {
    const size_t k0 = (size_t)kc * 64;
#pragma unroll
    for (int it = 0; it < AITER; ++it) {
      const int r = srow + it * 32;
      ra[it] = *(const uint4*)(A + (size_t)(m0 + r) * K + k0 + sseg * 8);
    }
#pragma unroll
    for (int it = 0; it < 4; ++it) {
      const int r = srow + it * 32;
      rb[it] = *(const uint4*)(Bt + (size_t)(n0 + r) * K + k0 + sseg * 8);
    }
  };
  auto store_ch = [&](int buf) {
#pragma unroll
    for (int it = 0; it < AITER; ++it) {
      const int r = srow + it * 32;
      const int sw = sseg ^ (r & 7);
      *(uint4*)(&As[buf][r * 64 + sw * 8]) = ra[it];
    }
#pragma unroll
    for (int it = 0; it < 4; ++it) {
      const int r = srow + it * 32;
      const int sw = sseg ^ (r & 7);
      *(uint4*)(&Bs[buf][r * 64 + sw * 8]) = rb[it];
    }
  };
  load_ch(0);
  store_ch(0);
  const int NKC = K >> 6;
  int cur = 0;
  for (int kc = 0; kc < NKC; ++kc) {
    __syncthreads();
    const bool pre = (kc + 1 < NKC);
    if (pre) load_ch(kc + 1);
#pragma unroll
    for (int ks = 0; ks < 2; ++ks) {
      bf16x8 af[4], bf_[NI];
#pragma unroll
      for (int mi = 0; mi < 4; ++mi) {
        const int r = wm * 64 + mi * 16 + lc;
        af[mi] = *(const bf16x8*)(&As[cur][r * 64 + (((ks * 4 + lg) ^ (r & 7)) * 8)]);
      }
#pragma unroll
      for (int ni = 0; ni < NI; ++ni) {
        const int r = wn * (NI * 16) + ni * 16 + lc;
        bf_[ni] = *(const bf16x8*)(&Bs[cur][r * 64 + (((ks * 4 + lg) ^ (r & 7)) * 8)]);
      }
#pragma unroll
      for (int mi = 0; mi < 4; ++mi)
#pragma unroll
        for (int ni = 0; ni < NI; ++ni)
          acc[mi][ni] = __builtin_amdgcn_mfma_f32_16x16x32_bf16(
              af[mi], bf_[ni], acc[mi][ni], 0, 0, 0);
    }
    if (pre) store_ch(cur ^ 1);
    cur ^= 1;
  }
#pragma unroll
  for (int mi = 0; mi < 4; ++mi) {
#pragma unroll
    for (int ni = 0; ni < NI; ++ni) {
      const int col = n0 + wn * (NI * 16) + ni * 16 + lc;
      const float bv = bias[col];
#pragma unroll
      for (int j = 0; j < 4; ++j) {
        const int row = m0 + wm * 64 + mi * 16 + lg * 4 + j;
        float c = acc[mi][ni][j] + bv;
        if constexpr (EPI == 2) {
          c = gelu_f(c);
        } else if constexpr (EPI == 3) {
          c += res[(size_t)row * N + col];
        } else if constexpr (EPI == 4) {
          c += res[(size_t)(row & 1023) * N + col];
        }
        if constexpr (EPI == 0 || EPI == 2)
          ((u16*)Cv)[(size_t)row * N + col] = f2bf(c);
        else
          ((float*)Cv)[(size_t)row * N + col] = c;
      }
    }
  }
}

// ================= LayerNorm (512), f32 in -> bf16 out, 4 rows/block =================
__global__ __launch_bounds__(256)
void ln_k(const float* __restrict__ in, const float* __restrict__ gam,
          const float* __restrict__ bet, u16* __restrict__ out) {
  const int row = blockIdx.x * 4 + (threadIdx.x >> 6);
  const int lane = threadIdx.x & 63;
  const float* p = in + (size_t)row * 512 + lane * 8;
  const float4 a = *(const float4*)p;
  const float4 b = *(const float4*)(p + 4);
  float s = a.x + a.y + a.z + a.w + b.x + b.y + b.z + b.w;
  float sq = a.x*a.x + a.y*a.y + a.z*a.z + a.w*a.w +
             b.x*b.x + b.y*b.y + b.z*b.z + b.w*b.w;
#pragma unroll
  for (int off = 32; off; off >>= 1) {
    s += __shfl_xor(s, off);
    sq += __shfl_xor(sq, off);
  }
  const float mean = s * (1.f / 512.f);
  const float rstd = rsqrtf(sq * (1.f / 512.f) - mean * mean + 1e-5f);
  const int c = lane * 8;
  const float v[8] = {a.x, a.y, a.z, a.w, b.x, b.y, b.z, b.w};
  float o[8];
#pragma unroll
  for (int j = 0; j < 8; ++j)
    o[j] = (v[j] - mean) * rstd * gam[c + j] + bet[c + j];
  uint4 pk;
  pk.x = pack2(o[0], o[1]); pk.y = pack2(o[2], o[3]);
  pk.z = pack2(o[4], o[5]); pk.w = pack2(o[6], o[7]);
  *(uint4*)(out + (size_t)row * 512 + c) = pk;
}

// ================= attention block 0: local window +-8 (bf16) =================
__global__ __launch_bounds__(64)
void attn_local(const u16* __restrict__ qkv, u16* __restrict__ out) {
  const int q = blockIdx.x, h = blockIdx.y, b = blockIdx.z;
  const int lane = threadIdx.x;
  __shared__ float qs[64];
  __shared__ float ks[17][65];
  __shared__ float vs[17][65];
  __shared__ float ss[17], ps[17];
  const u16* base = qkv + (size_t)(b * 1024) * 1536;
  qs[lane] = bf2f(base[(size_t)q * 1536 + h * 64 + lane]);
  int lo = q - 8; if (lo < 0) lo = 0;
  int hi = q + 8; if (hi > 1023) hi = 1023;
  const int nk = hi - lo + 1;
  for (int u = lane; u < nk * 16; u += 64) {
    const int j = u >> 4, seg = u & 15;
    const uint4 v = *(const uint4*)(base + (size_t)(lo + j) * 1536 + 512 + h * 64 +
                                    (seg < 8 ? seg * 8 : 512 + (seg - 8) * 8));
    float* dstrow = (seg < 8) ? &ks[j][(seg & 7) * 8] : &vs[j][(seg & 7) * 8];
    dstrow[0] = bf2f((u16)(v.x & 0xffffu)); dstrow[1] = bf2f((u16)(v.x >> 16));
    dstrow[2] = bf2f((u16)(v.y & 0xffffu)); dstrow[3] = bf2f((u16)(v.y >> 16));
    dstrow[4] = bf2f((u16)(v.z & 0xffffu)); dstrow[5] = bf2f((u16)(v.z >> 16));
    dstrow[6] = bf2f((u16)(v.w & 0xffffu)); dstrow[7] = bf2f((u16)(v.w >> 16));
  }
  __syncthreads();
  if (lane < nk) {
    float s = 0.f;
#pragma unroll
    for (int d = 0; d < 64; ++d) s = fmaf(qs[d], ks[lane][d], s);
    ss[lane] = s * 0.125f;
  }
  __syncthreads();
  float mx = -1e30f;
  for (int j = 0; j < nk; ++j) mx = fmaxf(mx, ss[j]);
  if (lane < nk) ps[lane] = expf(ss[lane] - mx);
  __syncthreads();
  float l = 0.f, o = 0.f;
  for (int j = 0; j < nk; ++j) { l += ps[j]; o = fmaf(ps[j], vs[j][lane], o); }
  out[(size_t)(b * 1024 + q) * 512 + h * 64 + lane] = f2bf(o / l);
}

// ===== attention block 1, fused: blocks <2048 copy v; blocks >=2048 full softmax ====
__global__ __launch_bounds__(256)
void attn_glob(const u16* __restrict__ qkv, u16* __restrict__ out) {
  __shared__ float qs[64];
  __shared__ float ps[1024];
  __shared__ float wred[8];
  __shared__ float osum[4][64];
  if (blockIdx.x < 2048) {
    const int i = blockIdx.x * 256 + threadIdx.x;
    const int row = i >> 6;
    const int col = (i & 63) * 8;
    const int q = row & 1023;
    if (q % 100 == 0) return;
    *(uint4*)(out + (size_t)row * 512 + col) =
        *(const uint4*)(qkv + (size_t)row * 1536 + 1024 + col);
    return;
  }
  const int l = blockIdx.x - 2048;          // 0..703
  const int q = (l % 11) * 100;
  const int h = (l / 11) & 7, b = l / 88;
  const int tid = threadIdx.x, lane = tid & 63, wave = tid >> 6;
  const u16* base = qkv + (size_t)(b * 1024) * 1536;
  if (tid < 64) qs[tid] = bf2f(base[(size_t)q * 1536 + h * 64 + tid]);
  __syncthreads();
  float sv[4];
  float mx = -1e30f;
#pragma unroll
  for (int i = 0; i < 4; ++i) {
    const int k = tid + i * 256;
    const u16* kr = base + (size_t)k * 1536 + 512 + h * 64;
    float s = 0.f;
#pragma unroll
    for (int seg = 0; seg < 8; ++seg)
      s += dot8(&qs[seg * 8], *(const uint4*)(kr + seg * 8));
    sv[i] = s * 0.125f;
    mx = fmaxf(mx, sv[i]);
  }
#pragma unroll
  for (int off = 32; off; off >>= 1) mx = fmaxf(mx, __shfl_xor(mx, off));
  if (lane == 0) wred[wave] = mx;
  __syncthreads();
  mx = fmaxf(fmaxf(wred[0], wred[1]), fmaxf(wred[2], wred[3]));
  float ls = 0.f;
#pragma unroll
  for (int i = 0; i < 4; ++i) {
    const float p = expf(sv[i] - mx);
    ps[tid + i * 256] = p;
    ls += p;
  }
#pragma unroll
  for (int off = 32; off; off >>= 1) ls += __shfl_xor(ls, off);
  if (lane == 0) wred[4 + wave] = ls;
  __syncthreads();
  const float lsum = wred[4] + wred[5] + wred[6] + wred[7];
  float o = 0.f;
  const u16* vb = base + 1024 + h * 64 + lane;
#pragma unroll 8
  for (int k = wave * 256; k < wave * 256 + 256; ++k)
    o = fmaf(ps[k], bf2f(vb[(size_t)k * 1536]), o);
  osum[wave][lane] = o;
  __syncthreads();
  if (wave == 0) {
    const float t = osum[0][lane] + osum[1][lane] + osum[2][lane] + osum[3][lane];
    out[(size_t)(b * 1024 + q) * 512 + h * 64 + lane] = f2bf(t / lsum);
  }
}

// ================= launch =================
extern "C" void kernel_launch(void* const* d_in, const int* in_sizes, int n_in,
                              void* d_out, int out_size, void* d_ws, size_t ws_size,
                              hipStream_t stream) {
  auto F = [&](int i) { return (const float*)d_in[i]; };
  const float* x = F(0);
  const float* proj_w = F(25); const float* proj_b = F(26);
  const float* w_in = F(27);  const float* b_in = F(28);
  const float* w_out = F(29); const float* b_out = F(30);
  const float* l1s = F(31); const float* l1b = F(32);
  const float* l2s = F(33); const float* l2b = F(34);
  const float* w1 = F(35); const float* b1 = F(36);
  const float* w2 = F(37); const float* b2 = F(38);

  char* wsb = (char*)d_ws;
  const size_t MB = 1024 * 1024;
  u16* projT = (u16*)(wsb + 0);
  u16* winT  = (u16*)(wsb + 1 * MB);
  u16* woutT = (u16*)(wsb + 4 * MB);
  u16* w1T   = (u16*)(wsb + 5 * MB);
  u16* w2T   = (u16*)(wsb + 9 * MB);
  u16* wp2   = (u16*)(wsb + 13 * MB);
  u16* zpad  = (u16*)(wsb + 13 * MB + 512 * 1024);  // 256B zero pad
  u16* wp3   = (u16*)(wsb + 14 * MB);
  u16* wp4   = (u16*)(wsb + 16 * MB);
  float* pe  = (float*)(wsb + 18 * MB);   // 1024x512 f32 = 2 MB
  char* bufA = wsb + 20 * MB;
  char* bufB = wsb + 68 * MB;
  float* h = (float*)d_out;

  u16* c1o = (u16*)bufA;
  u16* c2o = (u16*)bufB;
  u16* c3o = (u16*)bufA;
  u16* prA = (u16*)bufB;
  u16* xln = (u16*)bufB;
  u16* qkv = (u16*)(bufB + 9 * MB);
  u16* att = (u16*)bufA;
  u16* m1b = (u16*)(bufA + 9 * MB);

  // ---- fused weight prep + PE table + zpad (one launch) ----
  prep_all<<<13609, 256, 0, stream>>>(
      proj_w, w_in, w_out, w1, w2,
      F(7), F(9), F(12), F(13), F(15), F(18), F(19), F(21), F(24),
      projT, winT, woutT, w1T, w2T, wp2, wp3, wp4, pe, zpad);

  // ---- conv stack (NHWC bf16), 2-wave blocks, full-COUT waves ----
  conv1_k<<<dim3(4, 64, 8), 256, 0, stream>>>(x, F(1), F(2), F(3), F(4), F(5), F(6), c1o);
  conv_mfma<32, 64, 32, 64, 5, 2, 32, 2, 1, 0><<<dim3(256, 8), 128, 0, stream>>>(
      c1o, wp2, F(8), F(9), F(10), F(11), F(12), zpad, c2o);
  conv_mfma<64, 32, 16, 128, 7, 3, 64, 2, 1, 0><<<dim3(128, 8), 128, 0, stream>>>(
      c2o, wp3, F(14), F(15), F(16), F(17), F(18), zpad, c3o);
  conv_mfma<128, 16, 8, 128, 7, 3, 64, 2, 1, 1><<<dim3(64, 8), 128, 0, stream>>>(
      c3o, wp4, F(20), F(21), F(22), F(23), F(24), zpad, prA);

  // ---- proj + bias + posenc(table) -> h (f32) ----
  gemm_bf16<4, 128><<<256, 256, 0, stream>>>(prA, projT, proj_b, pe, h,
                                             8192, 512, 1024, 4);
  for (int i = 0; i < 2; ++i) {
    ln_k<<<2048, 256, 0, stream>>>(h, l1s + i * 512, l1b + i * 512, xln);
    gemm_bf16<0, 128><<<768, 256, 0, stream>>>(
        xln, winT + (size_t)i * 1536 * 512, b_in + i * 1536, nullptr, qkv,
        8192, 1536, 512, 12);
    if (i == 0) {
      attn_local<<<dim3(1024, 8, 8), 64, 0, stream>>>(qkv, att);
    } else {
      attn_glob<<<2752, 256, 0, stream>>>(qkv, att);
    }
    gemm_bf16<3, 128><<<256, 256, 0, stream>>>(
        att, woutT + (size_t)i * 512 * 512, b_out + i * 512, h, h,
        8192, 512, 512, 4);
    ln_k<<<2048, 256, 0, stream>>>(h, l2s + i * 512, l2b + i * 512, xln);
    gemm_bf16<2, 128><<<1024, 256, 0, stream>>>(
        xln, w1T + (size_t)i * 2048 * 512, b1 + i * 2048, nullptr, m1b,
        8192, 2048, 512, 16);
    gemm_bf16<3, 128><<<256, 256, 0, stream>>>(
        m1b, w2T + (size_t)i * 512 * 2048, b2 + i * 512, h, h,
        8192, 512, 2048, 4);
  }
}

// Round 10
// 1084.369 us; speedup vs baseline: 1.1452x; 1.1452x over previous
//
#include <hip/hip_runtime.h>
#include <math.h>

typedef unsigned short u16;
typedef unsigned int u32;
typedef __attribute__((ext_vector_type(8))) short bf16x8;
typedef __attribute__((ext_vector_type(4))) float f32x4;

#define DEV __device__ __forceinline__

DEV float gelu_f(float x) { return 0.5f * x * (1.0f + erff(x * 0.70710678118654752f)); }

DEV float bf2f(u16 b) {
  u32 u = ((u32)b) << 16;
  return __builtin_bit_cast(float, u);
}
DEV u16 f2bf(float f) {
  u32 u = __builtin_bit_cast(u32, f);
  u32 r = (u + 0x7fffu + ((u >> 16) & 1u)) >> 16;
  return (u16)r;
}
DEV u32 pack2(float a, float b) { return (u32)f2bf(a) | ((u32)f2bf(b) << 16); }

DEV float dot8(const float* __restrict__ q, uint4 v) {
  float s;
  s = q[0] * bf2f((u16)(v.x & 0xffffu));
  s = fmaf(q[1], bf2f((u16)(v.x >> 16)), s);
  s = fmaf(q[2], bf2f((u16)(v.y & 0xffffu)), s);
  s = fmaf(q[3], bf2f((u16)(v.y >> 16)), s);
  s = fmaf(q[4], bf2f((u16)(v.z & 0xffffu)), s);
  s = fmaf(q[5], bf2f((u16)(v.z >> 16)), s);
  s = fmaf(q[6], bf2f((u16)(v.w & 0xffffu)), s);
  s = fmaf(q[7], bf2f((u16)(v.w >> 16)), s);
  return s;
}

// ================= conv1: direct (CIN=1, k3), NHWC bf16 out =================
__global__ __launch_bounds__(256)
void conv1_k(const float* __restrict__ x, const float* __restrict__ w,
             const float* __restrict__ cbv, const float* __restrict__ gam,
             const float* __restrict__ bet, const float* __restrict__ mu,
             const float* __restrict__ var, u16* __restrict__ out) {
  const int t = blockIdx.x * 256 + threadIdx.x;
  const int fo = blockIdx.y;   // 64
  const int b = blockIdx.z;    // 8
  float xin[3][3];
#pragma unroll
  for (int kh = 0; kh < 3; ++kh) {
    const int fi = 2 * fo + kh - 1;
#pragma unroll
    for (int kw = 0; kw < 3; ++kw) {
      const int tt = t + kw - 1;
      xin[kh][kw] = ((unsigned)fi < 128u && (unsigned)tt < 1024u)
                        ? x[(size_t)(b * 128 + fi) * 1024 + tt] : 0.f;
    }
  }
  u16* dst = out + (((size_t)b * 64 + fo) * 1024 + t) * 32;
#pragma unroll
  for (int g = 0; g < 4; ++g) {
    float vals[8];
#pragma unroll
    for (int cc = 0; cc < 8; ++cc) {
      const int co = g * 8 + cc;
      float acc = 0.f;
#pragma unroll
      for (int kh = 0; kh < 3; ++kh)
#pragma unroll
        for (int kw = 0; kw < 3; ++kw)
          acc = fmaf(xin[kh][kw], w[co * 9 + kh * 3 + kw], acc);
      const float sc = gam[co] * rsqrtf(var[co] + 1e-5f);
      const float sh = (cbv[co] - mu[co]) * sc + bet[co];
      vals[cc] = gelu_f(acc * sc + sh);
    }
    uint4 v;
    v.x = pack2(vals[0], vals[1]); v.y = pack2(vals[2], vals[3]);
    v.z = pack2(vals[4], vals[5]); v.w = pack2(vals[6], vals[7]);
    *(uint4*)(dst + g * 8) = v;
  }
}

// ======= fused weight prep: all transposes + conv weight prep + PE table =======
__global__ __launch_bounds__(256)
void prep_all(const float* __restrict__ proj_w, const float* __restrict__ w_in,
              const float* __restrict__ w_out, const float* __restrict__ w1,
              const float* __restrict__ w2,
              const float* __restrict__ cw2, const float* __restrict__ g2,
              const float* __restrict__ v2,
              const float* __restrict__ cw3, const float* __restrict__ g3,
              const float* __restrict__ v3,
              const float* __restrict__ cw4, const float* __restrict__ g4,
              const float* __restrict__ v4,
              u16* __restrict__ projT, u16* __restrict__ winT,
              u16* __restrict__ woutT, u16* __restrict__ w1T,
              u16* __restrict__ w2T, u16* __restrict__ wp2,
              u16* __restrict__ wp3, u16* __restrict__ wp4,
              float* __restrict__ pe) {
  __shared__ float tile[32][33];
  const int bid = blockIdx.x, tid = threadIdx.x;
  const float* src = nullptr; u16* dst = nullptr;
  int K = 0, N = 0, t = 0;
  if (bid < 512) { src = proj_w; dst = projT; K = 1024; N = 512; t = bid; }
  else if (bid < 2048) {
    const int l = bid - 512, i = l / 768; t = l % 768;
    K = 512; N = 1536;
    src = w_in + (size_t)i * 512 * 1536; dst = winT + (size_t)i * 1536 * 512;
  } else if (bid < 2560) {
    const int l = bid - 2048, i = l / 256; t = l % 256;
    K = 512; N = 512;
    src = w_out + (size_t)i * 512 * 512; dst = woutT + (size_t)i * 512 * 512;
  } else if (bid < 4608) {
    const int l = bid - 2560, i = l / 1024; t = l % 1024;
    K = 512; N = 2048;
    src = w1 + (size_t)i * 512 * 2048; dst = w1T + (size_t)i * 2048 * 512;
  } else if (bid < 6656) {
    const int l = bid - 4608, i = l / 1024; t = l % 1024;
    K = 2048; N = 512;
    src = w2 + (size_t)i * 2048 * 512; dst = w2T + (size_t)i * 512 * 2048;
  }
  if (dst) {
    const int ntn = N >> 5;
    const int n0 = (t % ntn) * 32, k0 = (t / ntn) * 32;
    const int tx = tid & 31, ty = tid >> 5;
#pragma unroll
    for (int i = 0; i < 32; i += 8)
      tile[ty + i][tx] = src[(size_t)(k0 + ty + i) * N + n0 + tx];
    __syncthreads();
#pragma unroll
    for (int i = 0; i < 32; i += 8)
      dst[(size_t)(n0 + ty + i) * K + k0 + tx] = f2bf(tile[tx][ty + i]);
    return;
  }
  const float* w = nullptr; const float* gam = nullptr; const float* var = nullptr;
  u16* wp = nullptr; int COUT = 0, CIN = 0, Kk = 0, total = 0, idx = 0;
  if (bid < 6856) { w = cw2; gam = g2; var = v2; wp = wp2; COUT = 64; CIN = 32; Kk = 5; total = 51200; idx = (bid - 6656) * 256 + tid; }
  else if (bid < 8424) { w = cw3; gam = g3; var = v3; wp = wp3; COUT = 128; CIN = 64; Kk = 7; total = 401408; idx = (bid - 6856) * 256 + tid; }
  else if (bid < 11560) { w = cw4; gam = g4; var = v4; wp = wp4; COUT = 128; CIN = 128; Kk = 7; total = 802816; idx = (bid - 8424) * 256 + tid; }
  if (wp) {
    if (idx >= total) return;
    const int KB32 = CIN / 32;
    const int i = idx & 31;
    const int co = (idx >> 5) % COUT;
    const int rest = idx / (32 * COUT);
    const int kw = rest % Kk;
    const int kbh = rest / Kk;
    const int kb = kbh % KB32;
    const int kh = kbh / KB32;
    const int ci = kb * 32 + i;
    const float sc = gam[co] * rsqrtf(var[co] + 1e-5f);
    wp[idx] = f2bf(w[((size_t)(co * CIN + ci) * Kk + kh) * Kk + kw] * sc);
    return;
  }
  const int i = (bid - 11560) * 256 + tid;   // < 1024*512
  const int tt = i >> 9, d = i & 511;
  const float div = expf((float)(d & ~1) * (-0.017988946039015984f));
  const float ang = (float)tt * div;
  pe[i] = (d & 1) ? cosf(ang) : sinf(ang);
}

// ================= implicit-GEMM MFMA conv (NHWC), swizzled LDS =================
template<int CIN, int FIN, int FOUT, int COUT, int K, int PAD, int CHUNK,
         int WT, int WCO, int OUTMODE>
__global__ __launch_bounds__(WT * WCO * 64)
void conv_mfma(const u16* __restrict__ in, const u16* __restrict__ wp,
               const float* __restrict__ cbv, const float* __restrict__ gam,
               const float* __restrict__ bet, const float* __restrict__ mu,
               const float* __restrict__ var, u16* __restrict__ out) {
  constexpr int NT = WT * WCO * 64, TT = WT * 64;
  constexpr int NI = COUT / (WCO * 16);
  constexpr int XROWS = TT + 16;
  constexpr int KB32 = CIN / 32, NCB = CIN / CHUNK, KS = CHUNK / 32;
  constexpr int SEGS = CHUNK / 8, SMASK = SEGS - 1;
  constexpr int UNITS = XROWS * SEGS;
  constexpr int NITER = (UNITS + NT - 1) / NT;
  __shared__ u16 Xs[2][XROWS * CHUNK];
  const int ttiles = 1024 / TT;
  const int tt = blockIdx.x % ttiles, fo = blockIdx.x / ttiles;
  const int b = blockIdx.y;
  const int t0 = tt * TT;
  const int tid = threadIdx.x, lane = tid & 63;
  const int wave = tid >> 6;
  const int wt = wave % WT, wco = wave / WT;
  const int lc = lane & 15, lg = lane >> 4;
  const int khlo = max(0, PAD - 2 * fo);
  const int khhi = min(K, FIN + PAD - 2 * fo);
  const int nc = (khhi - khlo) * NCB;

  f32x4 acc[4][NI];
#pragma unroll
  for (int mi = 0; mi < 4; ++mi)
#pragma unroll
    for (int ni = 0; ni < NI; ++ni)
#pragma unroll
      for (int j = 0; j < 4; ++j) acc[mi][ni][j] = 0.f;

  uint4 regs[NITER];
  auto load_chunk = [&](int c) {
    const int kh = khlo + c / NCB;
    const int fi = 2 * fo + kh - PAD;
    const int cb0 = (c % NCB) * CHUNK;
    const u16* src = in + ((size_t)(b * FIN + fi) * 1024) * CIN + cb0;
#pragma unroll
    for (int it = 0; it < NITER; ++it) {
      const int u = tid + it * NT;
      uint4 v = {0u, 0u, 0u, 0u};
      if (u < UNITS) {
        const int r = u / SEGS, seg = u % SEGS;
        const int tg = t0 - 8 + r;
        if ((unsigned)tg < 1024u)
          v = *(const uint4*)(src + (size_t)tg * CIN + seg * 8);
      }
      regs[it] = v;
    }
  };
  auto store_chunk = [&](int buf) {
#pragma unroll
    for (int it = 0; it < NITER; ++it) {
      const int u = tid + it * NT;
      if (u < UNITS) {
        const int r = u / SEGS, seg = u % SEGS;
        const int sw = seg ^ (r & SMASK);
        *(uint4*)(&Xs[buf][r * CHUNK + sw * 8]) = regs[it];
      }
    }
  };

  load_chunk(0);
  store_chunk(0);
  int cur = 0;
  for (int c = 0; c < nc; ++c) {
    __syncthreads();
    const bool pre = (c + 1 < nc);
    if (pre) load_chunk(c + 1);
    const int kh = khlo + c / NCB;
    const int cbk = (c % NCB) * KS;
    const u16* xb = &Xs[cur][0];
#pragma unroll
    for (int kw = 0; kw < K; ++kw) {
#pragma unroll
      for (int ks = 0; ks < KS; ++ks) {
        const int kb32 = kh * KB32 + cbk + ks;
        bf16x8 bfr[NI];
#pragma unroll
        for (int ni = 0; ni < NI; ++ni)
          bfr[ni] = *(const bf16x8*)(wp +
              (((size_t)(kb32 * K + kw) * COUT) + (wco * (NI * 16) + ni * 16 + lc)) * 32 + lg * 8);
        bf16x8 afr[4];
#pragma unroll
        for (int mi = 0; mi < 4; ++mi) {
          const int r = wt * 64 + mi * 16 + lc + kw + (8 - PAD);
          const int sw = (ks * 4 + lg) ^ (r & SMASK);
          afr[mi] = *(const bf16x8*)(xb + r * CHUNK + sw * 8);
        }
#pragma unroll
        for (int mi = 0; mi < 4; ++mi)
#pragma unroll
          for (int ni = 0; ni < NI; ++ni)
            acc[mi][ni] = __builtin_amdgcn_mfma_f32_16x16x32_bf16(
                afr[mi], bfr[ni], acc[mi][ni], 0, 0, 0);
      }
    }
    if (pre) store_chunk(cur ^ 1);
    cur ^= 1;
  }
#pragma unroll
  for (int ni = 0; ni < NI; ++ni) {
    const int co = wco * (NI * 16) + ni * 16 + lc;
    const float sc = gam[co] * rsqrtf(var[co] + 1e-5f);
    const float sh = (cbv[co] - mu[co]) * sc + bet[co];
#pragma unroll
    for (int mi = 0; mi < 4; ++mi) {
#pragma unroll
      for (int j = 0; j < 4; ++j) {
        const int tg = t0 + wt * 64 + mi * 16 + lg * 4 + j;
        const float v = gelu_f(acc[mi][ni][j] + sh);
        size_t off;
        if (OUTMODE == 0)
          off = (((size_t)b * FOUT + fo) * 1024 + tg) * COUT + co;
        else
          off = ((size_t)b * 1024 + tg) * 1024 + (size_t)co * 8 + fo;
        out[off] = f2bf(v);
      }
    }
  }
}

// ======= bf16 MFMA GEMM, 128x128 tile, BK=64, XOR-swizzled LDS, XCD-chunked grid ==
template<int EPI, int MT>
__global__ __launch_bounds__(256)
void gemm_bf16(const u16* __restrict__ A, const u16* __restrict__ Bt,
               const float* __restrict__ bias, const float* __restrict__ res,
               void* __restrict__ Cv, int M, int N, int K, int ntn) {
  constexpr int WN = (MT == 128) ? 2 : 4;
  constexpr int NI = 128 / (WN * 16);
  constexpr int AITER = MT / 32;
  __shared__ u16 As[2][MT * 64];
  __shared__ u16 Bs[2][128 * 64];
  const int nwg = gridDim.x;
  const int q8 = nwg >> 3;
  const int idx = (blockIdx.x & 7) * q8 + (blockIdx.x >> 3);
  const int n0 = (idx % ntn) * 128, m0 = (idx / ntn) * MT;
  const int tid = threadIdx.x, lane = tid & 63, wave = tid >> 6;
  const int wm = wave / WN, wn = wave % WN;
  const int lc = lane & 15, lg = lane >> 4;
  const int srow = tid >> 3, sseg = tid & 7;
  f32x4 acc[4][NI];
#pragma unroll
  for (int mi = 0; mi < 4; ++mi)
#pragma unroll
    for (int ni = 0; ni < NI; ++ni)
#pragma unroll
      for (int j = 0; j < 4; ++j) acc[mi][ni][j] = 0.f;

  uint4 ra[AITER], rb[4];
  auto load_ch = [&](int kc) {
    const size_t k0 = (size_t)kc * 64;
#pragma unroll
    for (int it = 0; it < AITER; ++it) {
      const int r = srow + it * 32;
      ra[it] = *(const uint4*)(A + (size_t)(m0 + r) * K + k0 + sseg * 8);
    }
#pragma unroll
    for (int it = 0; it < 4; ++it) {
      const int r = srow + it * 32;
      rb[it] = *(const uint4*)(Bt + (size_t)(n0 + r) * K + k0 + sseg * 8);
    }
  };
  auto store_ch = [&](int buf) {
#pragma unroll
    for (int it = 0; it < AITER; ++it) {
      const int r = srow + it * 32;
      const int sw = sseg ^ (r & 7);
      *(uint4*)(&As[buf][r * 64 + sw * 8]) = ra[it];
    }
#pragma unroll
    for (int it = 0; it < 4; ++it) {
      const int r = srow + it * 32;
      const int sw = sseg ^ (r & 7);
      *(uint4*)(&Bs[buf][r * 64 + sw * 8]) = rb[it];
    }
  };
  load_ch(0);
  store_ch(0);
  const int NKC = K >> 6;
  int cur = 0;
  for (int kc = 0; kc < NKC; ++kc) {
    __syncthreads();
    const bool pre = (kc + 1 < NKC);
    if (pre) load_ch(kc + 1);
#pragma unroll
    for (int ks = 0; ks < 2; ++ks) {
      bf16x8 af[4], bf_[NI];
#pragma unroll
      for (int mi = 0; mi < 4; ++mi) {
        const int r = wm * 64 + mi * 16 + lc;
        af[mi] = *(const bf16x8*)(&As[cur][r * 64 + (((ks * 4 + lg) ^ (r & 7)) * 8)]);
      }
#pragma unroll
      for (int ni = 0; ni < NI; ++ni) {
        const int r = wn * (NI * 16) + ni * 16 + lc;
        bf_[ni] = *(const bf16x8*)(&Bs[cur][r * 64 + (((ks * 4 + lg) ^ (r & 7)) * 8)]);
      }
#pragma unroll
      for (int mi = 0; mi < 4; ++mi)
#pragma unroll
        for (int ni = 0; ni < NI; ++ni)
          acc[mi][ni] = __builtin_amdgcn_mfma_f32_16x16x32_bf16(
              af[mi], bf_[ni], acc[mi][ni], 0, 0, 0);
    }
    if (pre) store_ch(cur ^ 1);
    cur ^= 1;
  }
#pragma unroll
  for (int mi = 0; mi < 4; ++mi) {
#pragma unroll
    for (int ni = 0; ni < NI; ++ni) {
      const int col = n0 + wn * (NI * 16) + ni * 16 + lc;
      const float bv = bias[col];
#pragma unroll
      for (int j = 0; j < 4; ++j) {
        const int row = m0 + wm * 64 + mi * 16 + lg * 4 + j;
        float c = acc[mi][ni][j] + bv;
        if constexpr (EPI == 2) {
          c = gelu_f(c);
        } else if constexpr (EPI == 3) {
          c += res[(size_t)row * N + col];
        } else if constexpr (EPI == 4) {
          c += res[(size_t)(row & 1023) * N + col];
        }
        if constexpr (EPI == 0 || EPI == 2)
          ((u16*)Cv)[(size_t)row * N + col] = f2bf(c);
        else
          ((float*)Cv)[(size_t)row * N + col] = c;
      }
    }
  }
}

// ================= LayerNorm (512), f32 in -> bf16 out, 4 rows/block =================
__global__ __launch_bounds__(256)
void ln_k(const float* __restrict__ in, const float* __restrict__ gam,
          const float* __restrict__ bet, u16* __restrict__ out) {
  const int row = blockIdx.x * 4 + (threadIdx.x >> 6);
  const int lane = threadIdx.x & 63;
  const float* p = in + (size_t)row * 512 + lane * 8;
  const float4 a = *(const float4*)p;
  const float4 b = *(const float4*)(p + 4);
  float s = a.x + a.y + a.z + a.w + b.x + b.y + b.z + b.w;
  float sq = a.x*a.x + a.y*a.y + a.z*a.z + a.w*a.w +
             b.x*b.x + b.y*b.y + b.z*b.z + b.w*b.w;
#pragma unroll
  for (int off = 32; off; off >>= 1) {
    s += __shfl_xor(s, off);
    sq += __shfl_xor(sq, off);
  }
  const float mean = s * (1.f / 512.f);
  const float rstd = rsqrtf(sq * (1.f / 512.f) - mean * mean + 1e-5f);
  const int c = lane * 8;
  const float v[8] = {a.x, a.y, a.z, a.w, b.x, b.y, b.z, b.w};
  float o[8];
#pragma unroll
  for (int j = 0; j < 8; ++j)
    o[j] = (v[j] - mean) * rstd * gam[c + j] + bet[c + j];
  uint4 pk;
  pk.x = pack2(o[0], o[1]); pk.y = pack2(o[2], o[3]);
  pk.z = pack2(o[4], o[5]); pk.w = pack2(o[6], o[7]);
  *(uint4*)(out + (size_t)row * 512 + c) = pk;
}

// ====== attention block 0: local window +-8, 16 q per block (4 waves x 4 q) ======
// K/V rows [q0-8, q0+23] staged once; padded LDS rows avoid bank conflicts.
__global__ __launch_bounds__(256)
void attn_local(const u16* __restrict__ qkv, u16* __restrict__ out) {
  const int q0 = blockIdx.x * 16;           // 64 groups
  const int h = blockIdx.y, b = blockIdx.z;
  const int tid = threadIdx.x, lane = tid & 63, wave = tid >> 6;
  __shared__ float ksm[32][65];
  __shared__ float vsm[32][65];
  __shared__ float qsm[4][64];
  __shared__ float ssm[4][20];
  __shared__ float psm[4][20];
  const u16* base = qkv + (size_t)(b * 1024) * 1536;
  // stage 32 rows x (K 8 segs + V 8 segs) = 512 uint4, 2 per thread
#pragma unroll
  for (int it = 0; it < 2; ++it) {
    const int u = tid + it * 256;
    const int r = u >> 4, seg = u & 15;     // r in [0,32)
    const int rg = q0 - 8 + r;
    if ((unsigned)rg < 1024u) {
      const uint4 v = *(const uint4*)(base + (size_t)rg * 1536 + 512 + h * 64 +
                                      (seg < 8 ? seg * 8 : 512 + (seg - 8) * 8));
      float* dstrow = (seg < 8) ? &ksm[r][(seg & 7) * 8] : &vsm[r][(seg & 7) * 8];
      dstrow[0] = bf2f((u16)(v.x & 0xffffu)); dstrow[1] = bf2f((u16)(v.x >> 16));
      dstrow[2] = bf2f((u16)(v.y & 0xffffu)); dstrow[3] = bf2f((u16)(v.y >> 16));
      dstrow[4] = bf2f((u16)(v.z & 0xffffu)); dstrow[5] = bf2f((u16)(v.z >> 16));
      dstrow[6] = bf2f((u16)(v.w & 0xffffu)); dstrow[7] = bf2f((u16)(v.w >> 16));
    }
  }
  __syncthreads();
#pragma unroll 1
  for (int i = 0; i < 4; ++i) {             // uniform across all waves
    const int q = q0 + wave * 4 + i;
    qsm[wave][lane] = bf2f(base[(size_t)q * 1536 + h * 64 + lane]);
    __syncthreads();
    int lo = q - 8; if (lo < 0) lo = 0;
    int hi = q + 8; if (hi > 1023) hi = 1023;
    const int nk = hi - lo + 1;
    const int jb = lo - (q0 - 8);           // >= 0
    if (lane < nk) {
      float s = 0.f;
#pragma unroll
      for (int d = 0; d < 64; ++d) s = fmaf(qsm[wave][d], ksm[jb + lane][d], s);
      ssm[wave][lane] = s * 0.125f;
    }
    __syncthreads();
    float mx = -1e30f;
    for (int j = 0; j < nk; ++j) mx = fmaxf(mx, ssm[wave][j]);
    if (lane < nk) psm[wave][lane] = expf(ssm[wave][lane] - mx);
    __syncthreads();
    float l = 0.f, o = 0.f;
    for (int j = 0; j < nk; ++j) {
      const float p = psm[wave][j];
      l += p;
      o = fmaf(p, vsm[jb + j][lane], o);
    }
    out[(size_t)(b * 1024 + q) * 512 + h * 64 + lane] = f2bf(o / l);
    __syncthreads();
  }
}

// ===== attention block 1, fused: blocks <2048 copy v; blocks >=2048 full softmax ====
__global__ __launch_bounds__(256)
void attn_glob(const u16* __restrict__ qkv, u16* __restrict__ out) {
  __shared__ float qs[64];
  __shared__ float ps[1024];
  __shared__ float wred[8];
  __shared__ float osum[4][64];
  if (blockIdx.x < 2048) {
    const int i = blockIdx.x * 256 + threadIdx.x;
    const int row = i >> 6;
    const int col = (i & 63) * 8;
    const int q = row & 1023;
    if (q % 100 == 0) return;
    *(uint4*)(out + (size_t)row * 512 + col) =
        *(const uint4*)(qkv + (size_t)row * 1536 + 1024 + col);
    return;
  }
  const int l = blockIdx.x - 2048;          // 0..703
  const int q = (l % 11) * 100;
  const int h = (l / 11) & 7, b = l / 88;
  const int tid = threadIdx.x, lane = tid & 63, wave = tid >> 6;
  const u16* base = qkv + (size_t)(b * 1024) * 1536;
  if (tid < 64) qs[tid] = bf2f(base[(size_t)q * 1536 + h * 64 + tid]);
  __syncthreads();
  float sv[4];
  float mx = -1e30f;
#pragma unroll
  for (int i = 0; i < 4; ++i) {
    const int k = tid + i * 256;
    const u16* kr = base + (size_t)k * 1536 + 512 + h * 64;
    float s = 0.f;
#pragma unroll
    for (int seg = 0; seg < 8; ++seg)
      s += dot8(&qs[seg * 8], *(const uint4*)(kr + seg * 8));
    sv[i] = s * 0.125f;
    mx = fmaxf(mx, sv[i]);
  }
#pragma unroll
  for (int off = 32; off; off >>= 1) mx = fmaxf(mx, __shfl_xor(mx, off));
  if (lane == 0) wred[wave] = mx;
  __syncthreads();
  mx = fmaxf(fmaxf(wred[0], wred[1]), fmaxf(wred[2], wred[3]));
  float ls = 0.f;
#pragma unroll
  for (int i = 0; i < 4; ++i) {
    const float p = expf(sv[i] - mx);
    ps[tid + i * 256] = p;
    ls += p;
  }
#pragma unroll
  for (int off = 32; off; off >>= 1) ls += __shfl_xor(ls, off);
  if (lane == 0) wred[4 + wave] = ls;
  __syncthreads();
  const float lsum = wred[4] + wred[5] + wred[6] + wred[7];
  float o = 0.f;
  const u16* vb = base + 1024 + h * 64 + lane;
#pragma unroll 8
  for (int k = wave * 256; k < wave * 256 + 256; ++k)
    o = fmaf(ps[k], bf2f(vb[(size_t)k * 1536]), o);
  osum[wave][lane] = o;
  __syncthreads();
  if (wave == 0) {
    const float t = osum[0][lane] + osum[1][lane] + osum[2][lane] + osum[3][lane];
    out[(size_t)(b * 1024 + q) * 512 + h * 64 + lane] = f2bf(t / lsum);
  }
}

// ================= launch =================
extern "C" void kernel_launch(void* const* d_in, const int* in_sizes, int n_in,
                              void* d_out, int out_size, void* d_ws, size_t ws_size,
                              hipStream_t stream) {
  auto F = [&](int i) { return (const float*)d_in[i]; };
  const float* x = F(0);
  const float* proj_w = F(25); const float* proj_b = F(26);
  const float* w_in = F(27);  const float* b_in = F(28);
  const float* w_out = F(29); const float* b_out = F(30);
  const float* l1s = F(31); const float* l1b = F(32);
  const float* l2s = F(33); const float* l2b = F(34);
  const float* w1 = F(35); const float* b1 = F(36);
  const float* w2 = F(37); const float* b2 = F(38);

  char* wsb = (char*)d_ws;
  const size_t MB = 1024 * 1024;
  u16* projT = (u16*)(wsb + 0);
  u16* winT  = (u16*)(wsb + 1 * MB);
  u16* woutT = (u16*)(wsb + 4 * MB);
  u16* w1T   = (u16*)(wsb + 5 * MB);
  u16* w2T   = (u16*)(wsb + 9 * MB);
  u16* wp2   = (u16*)(wsb + 13 * MB);
  u16* wp3   = (u16*)(wsb + 14 * MB);
  u16* wp4   = (u16*)(wsb + 16 * MB);
  float* pe  = (float*)(wsb + 18 * MB);   // 1024x512 f32 = 2 MB
  char* bufA = wsb + 20 * MB;
  char* bufB = wsb + 68 * MB;
  float* h = (float*)d_out;

  u16* c1o = (u16*)bufA;
  u16* c2o = (u16*)bufB;
  u16* c3o = (u16*)bufA;
  u16* prA = (u16*)bufB;
  u16* xln = (u16*)bufB;
  u16* qkv = (u16*)(bufB + 9 * MB);
  u16* att = (u16*)bufA;
  u16* m1b = (u16*)(bufA + 9 * MB);

  // ---- fused weight prep + PE table (one launch) ----
  prep_all<<<13608, 256, 0, stream>>>(
      proj_w, w_in, w_out, w1, w2,
      F(7), F(9), F(12), F(13), F(15), F(18), F(19), F(21), F(24),
      projT, winT, woutT, w1T, w2T, wp2, wp3, wp4, pe);

  // ---- conv stack (NHWC bf16) ----
  conv1_k<<<dim3(4, 64, 8), 256, 0, stream>>>(x, F(1), F(2), F(3), F(4), F(5), F(6), c1o);
  conv_mfma<32, 64, 32, 64, 5, 2, 32, 2, 2, 0><<<dim3(256, 8), 256, 0, stream>>>(
      c1o, wp2, F(8), F(9), F(10), F(11), F(12), c2o);
  conv_mfma<64, 32, 16, 128, 7, 3, 64, 1, 4, 0><<<dim3(256, 8), 256, 0, stream>>>(
      c2o, wp3, F(14), F(15), F(16), F(17), F(18), c3o);
  conv_mfma<128, 16, 8, 128, 7, 3, 64, 1, 4, 1><<<dim3(128, 8), 256, 0, stream>>>(
      c3o, wp4, F(20), F(21), F(22), F(23), F(24), prA);

  // ---- proj + bias + posenc(table) -> h (f32) ----
  gemm_bf16<4, 128><<<256, 256, 0, stream>>>(prA, projT, proj_b, pe, h,
                                             8192, 512, 1024, 4);
  for (int i = 0; i < 2; ++i) {
    ln_k<<<2048, 256, 0, stream>>>(h, l1s + i * 512, l1b + i * 512, xln);
    gemm_bf16<0, 128><<<768, 256, 0, stream>>>(
        xln, winT + (size_t)i * 1536 * 512, b_in + i * 1536, nullptr, qkv,
        8192, 1536, 512, 12);
    if (i == 0) {
      attn_local<<<dim3(64, 8, 8), 256, 0, stream>>>(qkv, att);
    } else {
      attn_glob<<<2752, 256, 0, stream>>>(qkv, att);
    }
    gemm_bf16<3, 128><<<256, 256, 0, stream>>>(
        att, woutT + (size_t)i * 512 * 512, b_out + i * 512, h, h,
        8192, 512, 512, 4);
    ln_k<<<2048, 256, 0, stream>>>(h, l2s + i * 512, l2b + i * 512, xln);
    gemm_bf16<2, 128><<<1024, 256, 0, stream>>>(
        xln, w1T + (size_t)i * 2048 * 512, b1 + i * 2048, nullptr, m1b,
        8192, 2048, 512, 16);
    gemm_bf16<3, 128><<<256, 256, 0, stream>>>(
        m1b, w2T + (size_t)i * 512 * 2048, b2 + i * 512, h, h,
        8192, 512, 2048, 4);
  }
}

// Round 11
// 747.343 us; speedup vs baseline: 1.6616x; 1.4510x over previous
//
#include <hip/hip_runtime.h>
#include <math.h>

typedef unsigned short u16;
typedef unsigned int u32;
typedef __attribute__((ext_vector_type(8))) short bf16x8;
typedef __attribute__((ext_vector_type(4))) float f32x4;

#define DEV __device__ __forceinline__

DEV float gelu_f(float x) { return 0.5f * x * (1.0f + erff(x * 0.70710678118654752f)); }

DEV float bf2f(u16 b) {
  u32 u = ((u32)b) << 16;
  return __builtin_bit_cast(float, u);
}
DEV u16 f2bf(float f) {
  u32 u = __builtin_bit_cast(u32, f);
  u32 r = (u + 0x7fffu + ((u >> 16) & 1u)) >> 16;
  return (u16)r;
}
DEV u32 pack2(float a, float b) { return (u32)f2bf(a) | ((u32)f2bf(b) << 16); }

DEV void gload16(const u16* g, const u16* l) {
  __builtin_amdgcn_global_load_lds(
      (const __attribute__((address_space(1))) void*)g,
      (__attribute__((address_space(3))) void*)l, 16, 0, 0);
}

DEV float dot8(const float* __restrict__ q, uint4 v) {
  float s;
  s = q[0] * bf2f((u16)(v.x & 0xffffu));
  s = fmaf(q[1], bf2f((u16)(v.x >> 16)), s);
  s = fmaf(q[2], bf2f((u16)(v.y & 0xffffu)), s);
  s = fmaf(q[3], bf2f((u16)(v.y >> 16)), s);
  s = fmaf(q[4], bf2f((u16)(v.z & 0xffffu)), s);
  s = fmaf(q[5], bf2f((u16)(v.z >> 16)), s);
  s = fmaf(q[6], bf2f((u16)(v.w & 0xffffu)), s);
  s = fmaf(q[7], bf2f((u16)(v.w >> 16)), s);
  return s;
}

// ================= conv1: direct (CIN=1, k3), NHWC bf16 out =================
__global__ __launch_bounds__(256)
void conv1_k(const float* __restrict__ x, const float* __restrict__ w,
             const float* __restrict__ cbv, const float* __restrict__ gam,
             const float* __restrict__ bet, const float* __restrict__ mu,
             const float* __restrict__ var, u16* __restrict__ out) {
  const int t = blockIdx.x * 256 + threadIdx.x;
  const int fo = blockIdx.y;   // 64
  const int b = blockIdx.z;    // 8
  float xin[3][3];
#pragma unroll
  for (int kh = 0; kh < 3; ++kh) {
    const int fi = 2 * fo + kh - 1;
#pragma unroll
    for (int kw = 0; kw < 3; ++kw) {
      const int tt = t + kw - 1;
      xin[kh][kw] = ((unsigned)fi < 128u && (unsigned)tt < 1024u)
                        ? x[(size_t)(b * 128 + fi) * 1024 + tt] : 0.f;
    }
  }
  u16* dst = out + (((size_t)b * 64 + fo) * 1024 + t) * 32;
#pragma unroll
  for (int g = 0; g < 4; ++g) {
    float vals[8];
#pragma unroll
    for (int cc = 0; cc < 8; ++cc) {
      const int co = g * 8 + cc;
      float acc = 0.f;
#pragma unroll
      for (int kh = 0; kh < 3; ++kh)
#pragma unroll
        for (int kw = 0; kw < 3; ++kw)
          acc = fmaf(xin[kh][kw], w[co * 9 + kh * 3 + kw], acc);
      const float sc = gam[co] * rsqrtf(var[co] + 1e-5f);
      const float sh = (cbv[co] - mu[co]) * sc + bet[co];
      vals[cc] = gelu_f(acc * sc + sh);
    }
    uint4 v;
    v.x = pack2(vals[0], vals[1]); v.y = pack2(vals[2], vals[3]);
    v.z = pack2(vals[4], vals[5]); v.w = pack2(vals[6], vals[7]);
    *(uint4*)(dst + g * 8) = v;
  }
}

// ======= fused weight prep: transposes + conv weight prep + PE table + zpad =======
__global__ __launch_bounds__(256)
void prep_all(const float* __restrict__ proj_w, const float* __restrict__ w_in,
              const float* __restrict__ w_out, const float* __restrict__ w1,
              const float* __restrict__ w2,
              const float* __restrict__ cw2, const float* __restrict__ g2,
              const float* __restrict__ v2,
              const float* __restrict__ cw3, const float* __restrict__ g3,
              const float* __restrict__ v3,
              const float* __restrict__ cw4, const float* __restrict__ g4,
              const float* __restrict__ v4,
              u16* __restrict__ projT, u16* __restrict__ winT,
              u16* __restrict__ woutT, u16* __restrict__ w1T,
              u16* __restrict__ w2T, u16* __restrict__ wp2,
              u16* __restrict__ wp3, u16* __restrict__ wp4,
              float* __restrict__ pe, u16* __restrict__ zpad) {
  __shared__ float tile[32][33];
  const int bid = blockIdx.x, tid = threadIdx.x;
  if (bid == 13608) { if (tid < 128) zpad[tid] = 0; return; }
  const float* src = nullptr; u16* dst = nullptr;
  int K = 0, N = 0, t = 0;
  if (bid < 512) { src = proj_w; dst = projT; K = 1024; N = 512; t = bid; }
  else if (bid < 2048) {
    const int l = bid - 512, i = l / 768; t = l % 768;
    K = 512; N = 1536;
    src = w_in + (size_t)i * 512 * 1536; dst = winT + (size_t)i * 1536 * 512;
  } else if (bid < 2560) {
    const int l = bid - 2048, i = l / 256; t = l % 256;
    K = 512; N = 512;
    src = w_out + (size_t)i * 512 * 512; dst = woutT + (size_t)i * 512 * 512;
  } else if (bid < 4608) {
    const int l = bid - 2560, i = l / 1024; t = l % 1024;
    K = 512; N = 2048;
    src = w1 + (size_t)i * 512 * 2048; dst = w1T + (size_t)i * 2048 * 512;
  } else if (bid < 6656) {
    const int l = bid - 4608, i = l / 1024; t = l % 1024;
    K = 2048; N = 512;
    src = w2 + (size_t)i * 2048 * 512; dst = w2T + (size_t)i * 512 * 2048;
  }
  if (dst) {
    const int ntn = N >> 5;
    const int n0 = (t % ntn) * 32, k0 = (t / ntn) * 32;
    const int tx = tid & 31, ty = tid >> 5;
#pragma unroll
    for (int i = 0; i < 32; i += 8)
      tile[ty + i][tx] = src[(size_t)(k0 + ty + i) * N + n0 + tx];
    __syncthreads();
#pragma unroll
    for (int i = 0; i < 32; i += 8)
      dst[(size_t)(n0 + ty + i) * K + k0 + tx] = f2bf(tile[tx][ty + i]);
    return;
  }
  const float* w = nullptr; const float* gam = nullptr; const float* var = nullptr;
  u16* wp = nullptr; int COUT = 0, CIN = 0, Kk = 0, total = 0, idx = 0;
  if (bid < 6856) { w = cw2; gam = g2; var = v2; wp = wp2; COUT = 64; CIN = 32; Kk = 5; total = 51200; idx = (bid - 6656) * 256 + tid; }
  else if (bid < 8424) { w = cw3; gam = g3; var = v3; wp = wp3; COUT = 128; CIN = 64; Kk = 7; total = 401408; idx = (bid - 6856) * 256 + tid; }
  else if (bid < 11560) { w = cw4; gam = g4; var = v4; wp = wp4; COUT = 128; CIN = 128; Kk = 7; total = 802816; idx = (bid - 8424) * 256 + tid; }
  if (wp) {
    if (idx >= total) return;
    const int KB32 = CIN / 32;
    const int i = idx & 31;
    const int co = (idx >> 5) % COUT;
    const int rest = idx / (32 * COUT);
    const int kw = rest % Kk;
    const int kbh = rest / Kk;
    const int kb = kbh % KB32;
    const int kh = kbh / KB32;
    const int ci = kb * 32 + i;
    const float sc = gam[co] * rsqrtf(var[co] + 1e-5f);
    wp[idx] = f2bf(w[((size_t)(co * CIN + ci) * Kk + kh) * Kk + kw] * sc);
    return;
  }
  const int i = (bid - 11560) * 256 + tid;   // < 1024*512
  const int tt = i >> 9, d = i & 511;
  const float div = expf((float)(d & ~1) * (-0.017988946039015984f));
  const float ang = (float)tt * div;
  pe[i] = (d & 1) ? cosf(ang) : sinf(ang);
}

// ===== implicit-GEMM MFMA conv (NHWC), global_load_lds staging, swizzled LDS =====
// Proven tiles kept; only the staging method changed (reg-staged -> direct DMA).
template<int CIN, int FIN, int FOUT, int COUT, int K, int PAD, int CHUNK,
         int WT, int WCO, int OUTMODE>
__global__ __launch_bounds__(WT * WCO * 64)
void conv_mfma(const u16* __restrict__ in, const u16* __restrict__ wp,
               const float* __restrict__ cbv, const float* __restrict__ gam,
               const float* __restrict__ bet, const float* __restrict__ mu,
               const float* __restrict__ var, const u16* __restrict__ zpad,
               u16* __restrict__ out) {
  constexpr int NT = WT * WCO * 64, TT = WT * 64;
  constexpr int NI = COUT / (WCO * 16);
  constexpr int XROWS = TT + 16;
  constexpr int KB32 = CIN / 32, NCB = CIN / CHUNK, KS = CHUNK / 32;
  constexpr int SEGS = CHUNK / 8, SMASK = SEGS - 1;
  constexpr int UNITS = XROWS * SEGS;      // multiple of 64
  constexpr int WISS = UNITS / 64;
  constexpr int NW = NT / 64;
  static_assert(UNITS % 64 == 0, "units");
  __shared__ u16 Xs[2][XROWS * CHUNK];
  const int ttiles = 1024 / TT;
  const int tt = blockIdx.x % ttiles, fo = blockIdx.x / ttiles;
  const int b = blockIdx.y;
  const int t0 = tt * TT;
  const int tid = threadIdx.x, lane = tid & 63;
  const int wave = tid >> 6;
  const int wt = wave % WT, wco = wave / WT;
  const int lc = lane & 15, lg = lane >> 4;
  const int khlo = max(0, PAD - 2 * fo);
  const int khhi = min(K, FIN + PAD - 2 * fo);
  const int nc = (khhi - khlo) * NCB;

  f32x4 acc[4][NI];
#pragma unroll
  for (int mi = 0; mi < 4; ++mi)
#pragma unroll
    for (int ni = 0; ni < NI; ++ni)
#pragma unroll
      for (int j = 0; j < 4; ++j) acc[mi][ni][j] = 0.f;

  // stage chunk c into Xs[buf]: linear LDS dest, inverse-swizzled per-lane source
  auto stage = [&](int c, int buf) {
    const int kh = khlo + c / NCB;
    const int fi = 2 * fo + kh - PAD;
    const int cb0 = (c % NCB) * CHUNK;
    const u16* src = in + ((size_t)(b * FIN + fi) * 1024) * CIN + cb0;
    for (int iw = wave; iw < WISS; iw += NW) {
      const int u = iw * 64 + lane;
      const int r = u / SEGS, sw = u % SEGS;
      const int seg = sw ^ (r & SMASK);
      const int tg = t0 - 8 + r;
      const u16* g = ((unsigned)tg < 1024u)
                         ? src + (size_t)tg * CIN + seg * 8 : zpad;
      gload16(g, &Xs[buf][iw * 64 * 8]);
    }
  };

  stage(0, 0);
  int cur = 0;
  for (int c = 0; c < nc; ++c) {
    __syncthreads();                       // drains vmcnt: buf `cur` ready
    if (c + 1 < nc) stage(c + 1, cur ^ 1);
    const int kh = khlo + c / NCB;
    const int cbk = (c % NCB) * KS;
    const u16* xb = &Xs[cur][0];
#pragma unroll
    for (int kw = 0; kw < K; ++kw) {
#pragma unroll
      for (int ks = 0; ks < KS; ++ks) {
        const int kb32 = kh * KB32 + cbk + ks;
        bf16x8 bfr[NI];
#pragma unroll
        for (int ni = 0; ni < NI; ++ni)
          bfr[ni] = *(const bf16x8*)(wp +
              (((size_t)(kb32 * K + kw) * COUT) + (wco * (NI * 16) + ni * 16 + lc)) * 32 + lg * 8);
        bf16x8 afr[4];
#pragma unroll
        for (int mi = 0; mi < 4; ++mi) {
          const int r = wt * 64 + mi * 16 + lc + kw + (8 - PAD);
          const int sw = (ks * 4 + lg) ^ (r & SMASK);
          afr[mi] = *(const bf16x8*)(xb + r * CHUNK + sw * 8);
        }
#pragma unroll
        for (int mi = 0; mi < 4; ++mi)
#pragma unroll
          for (int ni = 0; ni < NI; ++ni)
            acc[mi][ni] = __builtin_amdgcn_mfma_f32_16x16x32_bf16(
                afr[mi], bfr[ni], acc[mi][ni], 0, 0, 0);
      }
    }
    cur ^= 1;
  }
#pragma unroll
  for (int ni = 0; ni < NI; ++ni) {
    const int co = wco * (NI * 16) + ni * 16 + lc;
    const float sc = gam[co] * rsqrtf(var[co] + 1e-5f);
    const float sh = (cbv[co] - mu[co]) * sc + bet[co];
#pragma unroll
    for (int mi = 0; mi < 4; ++mi) {
#pragma unroll
      for (int j = 0; j < 4; ++j) {
        const int tg = t0 + wt * 64 + mi * 16 + lg * 4 + j;
        const float v = gelu_f(acc[mi][ni][j] + sh);
        size_t off;
        if (OUTMODE == 0)
          off = (((size_t)b * FOUT + fo) * 1024 + tg) * COUT + co;
        else
          off = ((size_t)b * 1024 + tg) * 1024 + (size_t)co * 8 + fo;
        out[off] = f2bf(v);
      }
    }
  }
}

// == bf16 MFMA GEMM, 128x128, BK=64, global_load_lds staging, XOR-swizzled reads ==
template<int EPI>
__global__ __launch_bounds__(256)
void gemm_bf16(const u16* __restrict__ A, const u16* __restrict__ Bt,
               const float* __restrict__ bias, const float* __restrict__ res,
               void* __restrict__ Cv, int M, int N, int K, int ntn) {
  __shared__ u16 As[2][128 * 64];
  __shared__ u16 Bs[2][128 * 64];
  const int nwg = gridDim.x;
  const int q8 = nwg >> 3;
  const int idx = (blockIdx.x & 7) * q8 + (blockIdx.x >> 3);
  const int n0 = (idx % ntn) * 128, m0 = (idx / ntn) * 128;
  const int tid = threadIdx.x, lane = tid & 63, wave = tid >> 6;
  const int wm = wave >> 1, wn = wave & 1;
  const int lc = lane & 15, lg = lane >> 4;
  f32x4 acc[4][4];
#pragma unroll
  for (int mi = 0; mi < 4; ++mi)
#pragma unroll
    for (int ni = 0; ni < 4; ++ni)
#pragma unroll
      for (int j = 0; j < 4; ++j) acc[mi][ni][j] = 0.f;

  // stage K-chunk kc into buf: 16 wave-issues for A + 16 for B (4 per wave each)
  auto stage = [&](int kc, int buf) {
    const size_t k0 = (size_t)kc * 64;
#pragma unroll
    for (int iw = 0; iw < 4; ++iw) {
      const int u = (iw * 4 + wave) * 64 + lane;
      const int r = u >> 3, sw = u & 7;
      const int seg = sw ^ (r & 7);
      gload16(A + (size_t)(m0 + r) * K + k0 + seg * 8,
              &As[buf][(iw * 4 + wave) * 512]);
    }
#pragma unroll
    for (int iw = 0; iw < 4; ++iw) {
      const int u = (iw * 4 + wave) * 64 + lane;
      const int r = u >> 3, sw = u & 7;
      const int seg = sw ^ (r & 7);
      gload16(Bt + (size_t)(n0 + r) * K + k0 + seg * 8,
              &Bs[buf][(iw * 4 + wave) * 512]);
    }
  };
  stage(0, 0);
  const int NKC = K >> 6;
  int cur = 0;
  for (int kc = 0; kc < NKC; ++kc) {
    __syncthreads();
    if (kc + 1 < NKC) stage(kc + 1, cur ^ 1);
#pragma unroll
    for (int ks = 0; ks < 2; ++ks) {
      bf16x8 af[4], bf_[4];
#pragma unroll
      for (int mi = 0; mi < 4; ++mi) {
        const int r = wm * 64 + mi * 16 + lc;
        af[mi] = *(const bf16x8*)(&As[cur][r * 64 + (((ks * 4 + lg) ^ (r & 7)) * 8)]);
      }
#pragma unroll
      for (int ni = 0; ni < 4; ++ni) {
        const int r = wn * 64 + ni * 16 + lc;
        bf_[ni] = *(const bf16x8*)(&Bs[cur][r * 64 + (((ks * 4 + lg) ^ (r & 7)) * 8)]);
      }
#pragma unroll
      for (int mi = 0; mi < 4; ++mi)
#pragma unroll
        for (int ni = 0; ni < 4; ++ni)
          acc[mi][ni] = __builtin_amdgcn_mfma_f32_16x16x32_bf16(
              af[mi], bf_[ni], acc[mi][ni], 0, 0, 0);
    }
    cur ^= 1;
  }
#pragma unroll
  for (int mi = 0; mi < 4; ++mi) {
#pragma unroll
    for (int ni = 0; ni < 4; ++ni) {
      const int col = n0 + wn * 64 + ni * 16 + lc;
      const float bv = bias[col];
#pragma unroll
      for (int j = 0; j < 4; ++j) {
        const int row = m0 + wm * 64 + mi * 16 + lg * 4 + j;
        float c = acc[mi][ni][j] + bv;
        if constexpr (EPI == 2) {
          c = gelu_f(c);
        } else if constexpr (EPI == 3) {
          c += res[(size_t)row * N + col];
        } else if constexpr (EPI == 4) {
          c += res[(size_t)(row & 1023) * N + col];
        }
        if constexpr (EPI == 0 || EPI == 2)
          ((u16*)Cv)[(size_t)row * N + col] = f2bf(c);
        else
          ((float*)Cv)[(size_t)row * N + col] = c;
      }
    }
  }
}

// ================= LayerNorm (512), f32 in -> bf16 out, 4 rows/block =================
__global__ __launch_bounds__(256)
void ln_k(const float* __restrict__ in, const float* __restrict__ gam,
          const float* __restrict__ bet, u16* __restrict__ out) {
  const int row = blockIdx.x * 4 + (threadIdx.x >> 6);
  const int lane = threadIdx.x & 63;
  const float* p = in + (size_t)row * 512 + lane * 8;
  const float4 a = *(const float4*)p;
  const float4 b = *(const float4*)(p + 4);
  float s = a.x + a.y + a.z + a.w + b.x + b.y + b.z + b.w;
  float sq = a.x*a.x + a.y*a.y + a.z*a.z + a.w*a.w +
             b.x*b.x + b.y*b.y + b.z*b.z + b.w*b.w;
#pragma unroll
  for (int off = 32; off; off >>= 1) {
    s += __shfl_xor(s, off);
    sq += __shfl_xor(sq, off);
  }
  const float mean = s * (1.f / 512.f);
  const float rstd = rsqrtf(sq * (1.f / 512.f) - mean * mean + 1e-5f);
  const int c = lane * 8;
  const float v[8] = {a.x, a.y, a.z, a.w, b.x, b.y, b.z, b.w};
  float o[8];
#pragma unroll
  for (int j = 0; j < 8; ++j)
    o[j] = (v[j] - mean) * rstd * gam[c + j] + bet[c + j];
  uint4 pk;
  pk.x = pack2(o[0], o[1]); pk.y = pack2(o[2], o[3]);
  pk.z = pack2(o[4], o[5]); pk.w = pack2(o[6], o[7]);
  *(uint4*)(out + (size_t)row * 512 + c) = pk;
}

// ====== attention block 0: local window +-8, 16 q per block (4 waves x 4 q) ======
__global__ __launch_bounds__(256)
void attn_local(const u16* __restrict__ qkv, u16* __restrict__ out) {
  const int q0 = blockIdx.x * 16;
  const int h = blockIdx.y, b = blockIdx.z;
  const int tid = threadIdx.x, lane = tid & 63, wave = tid >> 6;
  __shared__ float ksm[32][65];
  __shared__ float vsm[32][65];
  __shared__ float qsm[4][64];
  __shared__ float ssm[4][20];
  __shared__ float psm[4][20];
  const u16* base = qkv + (size_t)(b * 1024) * 1536;
#pragma unroll
  for (int it = 0; it < 2; ++it) {
    const int u = tid + it * 256;
    const int r = u >> 4, seg = u & 15;
    const int rg = q0 - 8 + r;
    if ((unsigned)rg < 1024u) {
      const uint4 v = *(const uint4*)(base + (size_t)rg * 1536 + 512 + h * 64 +
                                      (seg < 8 ? seg * 8 : 512 + (seg - 8) * 8));
      float* dstrow = (seg < 8) ? &ksm[r][(seg & 7) * 8] : &vsm[r][(seg & 7) * 8];
      dstrow[0] = bf2f((u16)(v.x & 0xffffu)); dstrow[1] = bf2f((u16)(v.x >> 16));
      dstrow[2] = bf2f((u16)(v.y & 0xffffu)); dstrow[3] = bf2f((u16)(v.y >> 16));
      dstrow[4] = bf2f((u16)(v.z & 0xffffu)); dstrow[5] = bf2f((u16)(v.z >> 16));
      dstrow[6] = bf2f((u16)(v.w & 0xffffu)); dstrow[7] = bf2f((u16)(v.w >> 16));
    }
  }
  __syncthreads();
#pragma unroll 1
  for (int i = 0; i < 4; ++i) {
    const int q = q0 + wave * 4 + i;
    qsm[wave][lane] = bf2f(base[(size_t)q * 1536 + h * 64 + lane]);
    __syncthreads();
    int lo = q - 8; if (lo < 0) lo = 0;
    int hi = q + 8; if (hi > 1023) hi = 1023;
    const int nk = hi - lo + 1;
    const int jb = lo - (q0 - 8);
    if (lane < nk) {
      float s = 0.f;
#pragma unroll
      for (int d = 0; d < 64; ++d) s = fmaf(qsm[wave][d], ksm[jb + lane][d], s);
      ssm[wave][lane] = s * 0.125f;
    }
    __syncthreads();
    float mx = -1e30f;
    for (int j = 0; j < nk; ++j) mx = fmaxf(mx, ssm[wave][j]);
    if (lane < nk) psm[wave][lane] = expf(ssm[wave][lane] - mx);
    __syncthreads();
    float l = 0.f, o = 0.f;
    for (int j = 0; j < nk; ++j) {
      const float p = psm[wave][j];
      l += p;
      o = fmaf(p, vsm[jb + j][lane], o);
    }
    out[(size_t)(b * 1024 + q) * 512 + h * 64 + lane] = f2bf(o / l);
    __syncthreads();
  }
}

// ===== attention block 1, fused: blocks <2048 copy v; blocks >=2048 full softmax ====
__global__ __launch_bounds__(256)
void attn_glob(const u16* __restrict__ qkv, u16* __restrict__ out) {
  __shared__ float qs[64];
  __shared__ float ps[1024];
  __shared__ float wred[8];
  __shared__ float osum[4][64];
  if (blockIdx.x < 2048) {
    const int i = blockIdx.x * 256 + threadIdx.x;
    const int row = i >> 6;
    const int col = (i & 63) * 8;
    const int q = row & 1023;
    if (q % 100 == 0) return;
    *(uint4*)(out + (size_t)row * 512 + col) =
        *(const uint4*)(qkv + (size_t)row * 1536 + 1024 + col);
    return;
  }
  const int l = blockIdx.x - 2048;
  const int q = (l % 11) * 100;
  const int h = (l / 11) & 7, b = l / 88;
  const int tid = threadIdx.x, lane = tid & 63, wave = tid >> 6;
  const u16* base = qkv + (size_t)(b * 1024) * 1536;
  if (tid < 64) qs[tid] = bf2f(base[(size_t)q * 1536 + h * 64 + tid]);
  __syncthreads();
  float sv[4];
  float mx = -1e30f;
#pragma unroll
  for (int i = 0; i < 4; ++i) {
    const int k = tid + i * 256;
    const u16* kr = base + (size_t)k * 1536 + 512 + h * 64;
    float s = 0.f;
#pragma unroll
    for (int seg = 0; seg < 8; ++seg)
      s += dot8(&qs[seg * 8], *(const uint4*)(kr + seg * 8));
    sv[i] = s * 0.125f;
    mx = fmaxf(mx, sv[i]);
  }
#pragma unroll
  for (int off = 32; off; off >>= 1) mx = fmaxf(mx, __shfl_xor(mx, off));
  if (lane == 0) wred[wave] = mx;
  __syncthreads();
  mx = fmaxf(fmaxf(wred[0], wred[1]), fmaxf(wred[2], wred[3]));
  float ls = 0.f;
#pragma unroll
  for (int i = 0; i < 4; ++i) {
    const float p = expf(sv[i] - mx);
    ps[tid + i * 256] = p;
    ls += p;
  }
#pragma unroll
  for (int off = 32; off; off >>= 1) ls += __shfl_xor(ls, off);
  if (lane == 0) wred[4 + wave] = ls;
  __syncthreads();
  const float lsum = wred[4] + wred[5] + wred[6] + wred[7];
  float o = 0.f;
  const u16* vb = base + 1024 + h * 64 + lane;
#pragma unroll 8
  for (int k = wave * 256; k < wave * 256 + 256; ++k)
    o = fmaf(ps[k], bf2f(vb[(size_t)k * 1536]), o);
  osum[wave][lane] = o;
  __syncthreads();
  if (wave == 0) {
    const float t = osum[0][lane] + osum[1][lane] + osum[2][lane] + osum[3][lane];
    out[(size_t)(b * 1024 + q) * 512 + h * 64 + lane] = f2bf(t / lsum);
  }
}

// ================= launch =================
extern "C" void kernel_launch(void* const* d_in, const int* in_sizes, int n_in,
                              void* d_out, int out_size, void* d_ws, size_t ws_size,
                              hipStream_t stream) {
  auto F = [&](int i) { return (const float*)d_in[i]; };
  const float* x = F(0);
  const float* proj_w = F(25); const float* proj_b = F(26);
  const float* w_in = F(27);  const float* b_in = F(28);
  const float* w_out = F(29); const float* b_out = F(30);
  const float* l1s = F(31); const float* l1b = F(32);
  const float* l2s = F(33); const float* l2b = F(34);
  const float* w1 = F(35); const float* b1 = F(36);
  const float* w2 = F(37); const float* b2 = F(38);

  char* wsb = (char*)d_ws;
  const size_t MB = 1024 * 1024;
  u16* projT = (u16*)(wsb + 0);
  u16* winT  = (u16*)(wsb + 1 * MB);
  u16* woutT = (u16*)(wsb + 4 * MB);
  u16* w1T   = (u16*)(wsb + 5 * MB);
  u16* w2T   = (u16*)(wsb + 9 * MB);
  u16* wp2   = (u16*)(wsb + 13 * MB);
  u16* zpad  = (u16*)(wsb + 13 * MB + 512 * 1024);  // 256B zero pad
  u16* wp3   = (u16*)(wsb + 14 * MB);
  u16* wp4   = (u16*)(wsb + 16 * MB);
  float* pe  = (float*)(wsb + 18 * MB);   // 1024x512 f32 = 2 MB
  char* bufA = wsb + 20 * MB;
  char* bufB = wsb + 68 * MB;
  float* h = (float*)d_out;

  u16* c1o = (u16*)bufA;
  u16* c2o = (u16*)bufB;
  u16* c3o = (u16*)bufA;
  u16* prA = (u16*)bufB;
  u16* xln = (u16*)bufB;
  u16* qkv = (u16*)(bufB + 9 * MB);
  u16* att = (u16*)bufA;
  u16* m1b = (u16*)(bufA + 9 * MB);

  // ---- fused weight prep + PE table + zpad (one launch) ----
  prep_all<<<13609, 256, 0, stream>>>(
      proj_w, w_in, w_out, w1, w2,
      F(7), F(9), F(12), F(13), F(15), F(18), F(19), F(21), F(24),
      projT, winT, woutT, w1T, w2T, wp2, wp3, wp4, pe, zpad);

  // ---- conv stack (NHWC bf16) ----
  conv1_k<<<dim3(4, 64, 8), 256, 0, stream>>>(x, F(1), F(2), F(3), F(4), F(5), F(6), c1o);
  conv_mfma<32, 64, 32, 64, 5, 2, 32, 2, 2, 0><<<dim3(256, 8), 256, 0, stream>>>(
      c1o, wp2, F(8), F(9), F(10), F(11), F(12), zpad, c2o);
  conv_mfma<64, 32, 16, 128, 7, 3, 64, 1, 4, 0><<<dim3(256, 8), 256, 0, stream>>>(
      c2o, wp3, F(14), F(15), F(16), F(17), F(18), zpad, c3o);
  conv_mfma<128, 16, 8, 128, 7, 3, 64, 1, 4, 1><<<dim3(128, 8), 256, 0, stream>>>(
      c3o, wp4, F(20), F(21), F(22), F(23), F(24), zpad, prA);

  // ---- proj + bias + posenc(table) -> h (f32) ----
  gemm_bf16<4><<<256, 256, 0, stream>>>(prA, projT, proj_b, pe, h,
                                        8192, 512, 1024, 4);
  for (int i = 0; i < 2; ++i) {
    ln_k<<<2048, 256, 0, stream>>>(h, l1s + i * 512, l1b + i * 512, xln);
    gemm_bf16<0><<<768, 256, 0, stream>>>(
        xln, winT + (size_t)i * 1536 * 512, b_in + i * 1536, nullptr, qkv,
        8192, 1536, 512, 12);
    if (i == 0) {
      attn_local<<<dim3(64, 8, 8), 256, 0, stream>>>(qkv, att);
    } else {
      attn_glob<<<2752, 256, 0, stream>>>(qkv, att);
    }
    gemm_bf16<3><<<256, 256, 0, stream>>>(
        att, woutT + (size_t)i * 512 * 512, b_out + i * 512, h, h,
        8192, 512, 512, 4);
    ln_k<<<2048, 256, 0, stream>>>(h, l2s + i * 512, l2b + i * 512, xln);
    gemm_bf16<2><<<1024, 256, 0, stream>>>(
        xln, w1T + (size_t)i * 2048 * 512, b1 + i * 2048, nullptr, m1b,
        8192, 2048, 512, 16);
    gemm_bf16<3><<<256, 256, 0, stream>>>(
        m1b, w2T + (size_t)i * 512 * 2048, b2 + i * 512, h, h,
        8192, 512, 2048, 4);
  }
}

// Round 12
// 729.678 us; speedup vs baseline: 1.7019x; 1.0242x over previous
//
#include <hip/hip_runtime.h>
#include <math.h>

typedef unsigned short u16;
typedef unsigned int u32;
typedef __attribute__((ext_vector_type(8))) short bf16x8;
typedef __attribute__((ext_vector_type(4))) float f32x4;

#define DEV __device__ __forceinline__

DEV float gelu_f(float x) { return 0.5f * x * (1.0f + erff(x * 0.70710678118654752f)); }

DEV float bf2f(u16 b) {
  u32 u = ((u32)b) << 16;
  return __builtin_bit_cast(float, u);
}
DEV u16 f2bf(float f) {
  u32 u = __builtin_bit_cast(u32, f);
  u32 r = (u + 0x7fffu + ((u >> 16) & 1u)) >> 16;
  return (u16)r;
}
DEV u32 pack2(float a, float b) { return (u32)f2bf(a) | ((u32)f2bf(b) << 16); }

DEV void gload16(const u16* g, const u16* l) {
  __builtin_amdgcn_global_load_lds(
      (const __attribute__((address_space(1))) void*)g,
      (__attribute__((address_space(3))) void*)l, 16, 0, 0);
}

DEV float dot8(const float* __restrict__ q, uint4 v) {
  float s;
  s = q[0] * bf2f((u16)(v.x & 0xffffu));
  s = fmaf(q[1], bf2f((u16)(v.x >> 16)), s);
  s = fmaf(q[2], bf2f((u16)(v.y & 0xffffu)), s);
  s = fmaf(q[3], bf2f((u16)(v.y >> 16)), s);
  s = fmaf(q[4], bf2f((u16)(v.z & 0xffffu)), s);
  s = fmaf(q[5], bf2f((u16)(v.z >> 16)), s);
  s = fmaf(q[6], bf2f((u16)(v.w & 0xffffu)), s);
  s = fmaf(q[7], bf2f((u16)(v.w >> 16)), s);
  return s;
}

// ================= conv1: direct (CIN=1, k3), NHWC bf16 out =================
__global__ __launch_bounds__(256)
void conv1_k(const float* __restrict__ x, const float* __restrict__ w,
             const float* __restrict__ cbv, const float* __restrict__ gam,
             const float* __restrict__ bet, const float* __restrict__ mu,
             const float* __restrict__ var, u16* __restrict__ out) {
  const int t = blockIdx.x * 256 + threadIdx.x;
  const int fo = blockIdx.y;   // 64
  const int b = blockIdx.z;    // 8
  float xin[3][3];
#pragma unroll
  for (int kh = 0; kh < 3; ++kh) {
    const int fi = 2 * fo + kh - 1;
#pragma unroll
    for (int kw = 0; kw < 3; ++kw) {
      const int tt = t + kw - 1;
      xin[kh][kw] = ((unsigned)fi < 128u && (unsigned)tt < 1024u)
                        ? x[(size_t)(b * 128 + fi) * 1024 + tt] : 0.f;
    }
  }
  u16* dst = out + (((size_t)b * 64 + fo) * 1024 + t) * 32;
#pragma unroll
  for (int g = 0; g < 4; ++g) {
    float vals[8];
#pragma unroll
    for (int cc = 0; cc < 8; ++cc) {
      const int co = g * 8 + cc;
      float acc = 0.f;
#pragma unroll
      for (int kh = 0; kh < 3; ++kh)
#pragma unroll
        for (int kw = 0; kw < 3; ++kw)
          acc = fmaf(xin[kh][kw], w[co * 9 + kh * 3 + kw], acc);
      const float sc = gam[co] * rsqrtf(var[co] + 1e-5f);
      const float sh = (cbv[co] - mu[co]) * sc + bet[co];
      vals[cc] = gelu_f(acc * sc + sh);
    }
    uint4 v;
    v.x = pack2(vals[0], vals[1]); v.y = pack2(vals[2], vals[3]);
    v.z = pack2(vals[4], vals[5]); v.w = pack2(vals[6], vals[7]);
    *(uint4*)(dst + g * 8) = v;
  }
}

// ======= fused weight prep: transposes + conv weight prep + PE table + zpad =======
__global__ __launch_bounds__(256)
void prep_all(const float* __restrict__ proj_w, const float* __restrict__ w_in,
              const float* __restrict__ w_out, const float* __restrict__ w1,
              const float* __restrict__ w2,
              const float* __restrict__ cw2, const float* __restrict__ g2,
              const float* __restrict__ v2,
              const float* __restrict__ cw3, const float* __restrict__ g3,
              const float* __restrict__ v3,
              const float* __restrict__ cw4, const float* __restrict__ g4,
              const float* __restrict__ v4,
              u16* __restrict__ projT, u16* __restrict__ winT,
              u16* __restrict__ woutT, u16* __restrict__ w1T,
              u16* __restrict__ w2T, u16* __restrict__ wp2,
              u16* __restrict__ wp3, u16* __restrict__ wp4,
              float* __restrict__ pe, u16* __restrict__ zpad) {
  __shared__ float tile[32][33];
  const int bid = blockIdx.x, tid = threadIdx.x;
  if (bid == 13608) { if (tid < 128) zpad[tid] = 0; return; }
  const float* src = nullptr; u16* dst = nullptr;
  int K = 0, N = 0, t = 0;
  if (bid < 512) { src = proj_w; dst = projT; K = 1024; N = 512; t = bid; }
  else if (bid < 2048) {
    const int l = bid - 512, i = l / 768; t = l % 768;
    K = 512; N = 1536;
    src = w_in + (size_t)i * 512 * 1536; dst = winT + (size_t)i * 1536 * 512;
  } else if (bid < 2560) {
    const int l = bid - 2048, i = l / 256; t = l % 256;
    K = 512; N = 512;
    src = w_out + (size_t)i * 512 * 512; dst = woutT + (size_t)i * 512 * 512;
  } else if (bid < 4608) {
    const int l = bid - 2560, i = l / 1024; t = l % 1024;
    K = 512; N = 2048;
    src = w1 + (size_t)i * 512 * 2048; dst = w1T + (size_t)i * 2048 * 512;
  } else if (bid < 6656) {
    const int l = bid - 4608, i = l / 1024; t = l % 1024;
    K = 2048; N = 512;
    src = w2 + (size_t)i * 2048 * 512; dst = w2T + (size_t)i * 512 * 2048;
  }
  if (dst) {
    const int ntn = N >> 5;
    const int n0 = (t % ntn) * 32, k0 = (t / ntn) * 32;
    const int tx = tid & 31, ty = tid >> 5;
#pragma unroll
    for (int i = 0; i < 32; i += 8)
      tile[ty + i][tx] = src[(size_t)(k0 + ty + i) * N + n0 + tx];
    __syncthreads();
#pragma unroll
    for (int i = 0; i < 32; i += 8)
      dst[(size_t)(n0 + ty + i) * K + k0 + tx] = f2bf(tile[tx][ty + i]);
    return;
  }
  const float* w = nullptr; const float* gam = nullptr; const float* var = nullptr;
  u16* wp = nullptr; int COUT = 0, CIN = 0, Kk = 0, total = 0, idx = 0;
  if (bid < 6856) { w = cw2; gam = g2; var = v2; wp = wp2; COUT = 64; CIN = 32; Kk = 5; total = 51200; idx = (bid - 6656) * 256 + tid; }
  else if (bid < 8424) { w = cw3; gam = g3; var = v3; wp = wp3; COUT = 128; CIN = 64; Kk = 7; total = 401408; idx = (bid - 6856) * 256 + tid; }
  else if (bid < 11560) { w = cw4; gam = g4; var = v4; wp = wp4; COUT = 128; CIN = 128; Kk = 7; total = 802816; idx = (bid - 8424) * 256 + tid; }
  if (wp) {
    if (idx >= total) return;
    const int KB32 = CIN / 32;
    const int i = idx & 31;
    const int co = (idx >> 5) % COUT;
    const int rest = idx / (32 * COUT);
    const int kw = rest % Kk;
    const int kbh = rest / Kk;
    const int kb = kbh % KB32;
    const int kh = kbh / KB32;
    const int ci = kb * 32 + i;
    const float sc = gam[co] * rsqrtf(var[co] + 1e-5f);
    wp[idx] = f2bf(w[((size_t)(co * CIN + ci) * Kk + kh) * Kk + kw] * sc);
    return;
  }
  const int i = (bid - 11560) * 256 + tid;   // < 1024*512
  const int tt = i >> 9, d = i & 511;
  const float div = expf((float)(d & ~1) * (-0.017988946039015984f));
  const float ang = (float)tt * div;
  pe[i] = (d & 1) ? cosf(ang) : sinf(ang);
}

// ===== implicit-GEMM MFMA conv (NHWC), global_load_lds staging, swizzled LDS =====
template<int CIN, int FIN, int FOUT, int COUT, int K, int PAD, int CHUNK,
         int WT, int WCO, int OUTMODE>
__global__ __launch_bounds__(WT * WCO * 64)
void conv_mfma(const u16* __restrict__ in, const u16* __restrict__ wp,
               const float* __restrict__ cbv, const float* __restrict__ gam,
               const float* __restrict__ bet, const float* __restrict__ mu,
               const float* __restrict__ var, const u16* __restrict__ zpad,
               u16* __restrict__ out) {
  constexpr int NT = WT * WCO * 64, TT = WT * 64;
  constexpr int NI = COUT / (WCO * 16);
  constexpr int XROWS = TT + 16;
  constexpr int KB32 = CIN / 32, NCB = CIN / CHUNK, KS = CHUNK / 32;
  constexpr int SEGS = CHUNK / 8, SMASK = SEGS - 1;
  constexpr int UNITS = XROWS * SEGS;      // multiple of 64
  constexpr int WISS = UNITS / 64;
  constexpr int NW = NT / 64;
  static_assert(UNITS % 64 == 0, "units");
  __shared__ u16 Xs[2][XROWS * CHUNK];
  const int ttiles = 1024 / TT;
  const int tt = blockIdx.x % ttiles, fo = blockIdx.x / ttiles;
  const int b = blockIdx.y;
  const int t0 = tt * TT;
  const int tid = threadIdx.x, lane = tid & 63;
  const int wave = tid >> 6;
  const int wt = wave % WT, wco = wave / WT;
  const int lc = lane & 15, lg = lane >> 4;
  const int khlo = max(0, PAD - 2 * fo);
  const int khhi = min(K, FIN + PAD - 2 * fo);
  const int nc = (khhi - khlo) * NCB;

  f32x4 acc[4][NI];
#pragma unroll
  for (int mi = 0; mi < 4; ++mi)
#pragma unroll
    for (int ni = 0; ni < NI; ++ni)
#pragma unroll
      for (int j = 0; j < 4; ++j) acc[mi][ni][j] = 0.f;

  auto stage = [&](int c, int buf) {
    const int kh = khlo + c / NCB;
    const int fi = 2 * fo + kh - PAD;
    const int cb0 = (c % NCB) * CHUNK;
    const u16* src = in + ((size_t)(b * FIN + fi) * 1024) * CIN + cb0;
    for (int iw = wave; iw < WISS; iw += NW) {
      const int u = iw * 64 + lane;
      const int r = u / SEGS, sw = u % SEGS;
      const int seg = sw ^ (r & SMASK);
      const int tg = t0 - 8 + r;
      const u16* g = ((unsigned)tg < 1024u)
                         ? src + (size_t)tg * CIN + seg * 8 : zpad;
      gload16(g, &Xs[buf][iw * 64 * 8]);
    }
  };

  stage(0, 0);
  int cur = 0;
  for (int c = 0; c < nc; ++c) {
    __syncthreads();
    if (c + 1 < nc) stage(c + 1, cur ^ 1);
    const int kh = khlo + c / NCB;
    const int cbk = (c % NCB) * KS;
    const u16* xb = &Xs[cur][0];
#pragma unroll
    for (int kw = 0; kw < K; ++kw) {
#pragma unroll
      for (int ks = 0; ks < KS; ++ks) {
        const int kb32 = kh * KB32 + cbk + ks;
        bf16x8 bfr[NI];
#pragma unroll
        for (int ni = 0; ni < NI; ++ni)
          bfr[ni] = *(const bf16x8*)(wp +
              (((size_t)(kb32 * K + kw) * COUT) + (wco * (NI * 16) + ni * 16 + lc)) * 32 + lg * 8);
        bf16x8 afr[4];
#pragma unroll
        for (int mi = 0; mi < 4; ++mi) {
          const int r = wt * 64 + mi * 16 + lc + kw + (8 - PAD);
          const int sw = (ks * 4 + lg) ^ (r & SMASK);
          afr[mi] = *(const bf16x8*)(xb + r * CHUNK + sw * 8);
        }
#pragma unroll
        for (int mi = 0; mi < 4; ++mi)
#pragma unroll
          for (int ni = 0; ni < NI; ++ni)
            acc[mi][ni] = __builtin_amdgcn_mfma_f32_16x16x32_bf16(
                afr[mi], bfr[ni], acc[mi][ni], 0, 0, 0);
      }
    }
    cur ^= 1;
  }
#pragma unroll
  for (int ni = 0; ni < NI; ++ni) {
    const int co = wco * (NI * 16) + ni * 16 + lc;
    const float sc = gam[co] * rsqrtf(var[co] + 1e-5f);
    const float sh = (cbv[co] - mu[co]) * sc + bet[co];
#pragma unroll
    for (int mi = 0; mi < 4; ++mi) {
#pragma unroll
      for (int j = 0; j < 4; ++j) {
        const int tg = t0 + wt * 64 + mi * 16 + lg * 4 + j;
        const float v = gelu_f(acc[mi][ni][j] + sh);
        size_t off;
        if (OUTMODE == 0)
          off = (((size_t)b * FOUT + fo) * 1024 + tg) * COUT + co;
        else
          off = ((size_t)b * 1024 + tg) * 1024 + (size_t)co * 8 + fo;
        out[off] = f2bf(v);
      }
    }
  }
}

// == bf16 MFMA GEMM, 128x128 tile, templated BK, gload_lds staging, swizzled reads ==
// BK=64: LDS 64KB (2 blocks/CU) for large grids. BK=128: LDS 128KB, half the
// barriers — for grid-256 (1 block/CU) N=512 GEMMs where occupancy can't drop.
template<int EPI, int BK>
__global__ __launch_bounds__(256)
void gemm_bf16(const u16* __restrict__ A, const u16* __restrict__ Bt,
               const float* __restrict__ bias, const float* __restrict__ res,
               void* __restrict__ Cv, int M, int N, int K, int ntn) {
  constexpr int SEGS = BK / 8, SM = SEGS - 1, KSN = BK / 32;
  constexpr int WI = SEGS / 2;          // wave-issues per operand per wave
  __shared__ u16 As[2][128 * BK];
  __shared__ u16 Bs[2][128 * BK];
  const int nwg = gridDim.x;
  const int q8 = nwg >> 3;
  const int idx = (blockIdx.x & 7) * q8 + (blockIdx.x >> 3);
  const int n0 = (idx % ntn) * 128, m0 = (idx / ntn) * 128;
  const int tid = threadIdx.x, lane = tid & 63, wave = tid >> 6;
  const int wm = wave >> 1, wn = wave & 1;
  const int lc = lane & 15, lg = lane >> 4;
  f32x4 acc[4][4];
#pragma unroll
  for (int mi = 0; mi < 4; ++mi)
#pragma unroll
    for (int ni = 0; ni < 4; ++ni)
#pragma unroll
      for (int j = 0; j < 4; ++j) acc[mi][ni][j] = 0.f;

  auto stage = [&](int kc, int buf) {
    const size_t k0 = (size_t)kc * BK;
#pragma unroll
    for (int iw = 0; iw < WI; ++iw) {
      const int is = iw * 4 + wave;
      const int u = is * 64 + lane;
      const int r = u / SEGS, sw = u % SEGS;
      const int seg = sw ^ (r & SM);
      gload16(A + (size_t)(m0 + r) * K + k0 + seg * 8, &As[buf][is * 512]);
    }
#pragma unroll
    for (int iw = 0; iw < WI; ++iw) {
      const int is = iw * 4 + wave;
      const int u = is * 64 + lane;
      const int r = u / SEGS, sw = u % SEGS;
      const int seg = sw ^ (r & SM);
      gload16(Bt + (size_t)(n0 + r) * K + k0 + seg * 8, &Bs[buf][is * 512]);
    }
  };
  stage(0, 0);
  const int NKC = K / BK;
  int cur = 0;
  for (int kc = 0; kc < NKC; ++kc) {
    __syncthreads();
    if (kc + 1 < NKC) stage(kc + 1, cur ^ 1);
#pragma unroll
    for (int ks = 0; ks < KSN; ++ks) {
      bf16x8 af[4], bf_[4];
#pragma unroll
      for (int mi = 0; mi < 4; ++mi) {
        const int r = wm * 64 + mi * 16 + lc;
        af[mi] = *(const bf16x8*)(&As[cur][r * BK + (((ks * 4 + lg) ^ (r & SM)) * 8)]);
      }
#pragma unroll
      for (int ni = 0; ni < 4; ++ni) {
        const int r = wn * 64 + ni * 16 + lc;
        bf_[ni] = *(const bf16x8*)(&Bs[cur][r * BK + (((ks * 4 + lg) ^ (r & SM)) * 8)]);
      }
#pragma unroll
      for (int mi = 0; mi < 4; ++mi)
#pragma unroll
        for (int ni = 0; ni < 4; ++ni)
          acc[mi][ni] = __builtin_amdgcn_mfma_f32_16x16x32_bf16(
              af[mi], bf_[ni], acc[mi][ni], 0, 0, 0);
    }
    cur ^= 1;
  }
#pragma unroll
  for (int mi = 0; mi < 4; ++mi) {
#pragma unroll
    for (int ni = 0; ni < 4; ++ni) {
      const int col = n0 + wn * 64 + ni * 16 + lc;
      const float bv = bias[col];
#pragma unroll
      for (int j = 0; j < 4; ++j) {
        const int row = m0 + wm * 64 + mi * 16 + lg * 4 + j;
        float c = acc[mi][ni][j] + bv;
        if constexpr (EPI == 2) {
          c = gelu_f(c);
        } else if constexpr (EPI == 3) {
          c += res[(size_t)row * N + col];
        } else if constexpr (EPI == 4) {
          c += res[(size_t)(row & 1023) * N + col];
        }
        if constexpr (EPI == 0 || EPI == 2)
          ((u16*)Cv)[(size_t)row * N + col] = f2bf(c);
        else
          ((float*)Cv)[(size_t)row * N + col] = c;
      }
    }
  }
}

// ================= LayerNorm (512), f32 in -> bf16 out, 4 rows/block =================
__global__ __launch_bounds__(256)
void ln_k(const float* __restrict__ in, const float* __restrict__ gam,
          const float* __restrict__ bet, u16* __restrict__ out) {
  const int row = blockIdx.x * 4 + (threadIdx.x >> 6);
  const int lane = threadIdx.x & 63;
  const float* p = in + (size_t)row * 512 + lane * 8;
  const float4 a = *(const float4*)p;
  const float4 b = *(const float4*)(p + 4);
  float s = a.x + a.y + a.z + a.w + b.x + b.y + b.z + b.w;
  float sq = a.x*a.x + a.y*a.y + a.z*a.z + a.w*a.w +
             b.x*b.x + b.y*b.y + b.z*b.z + b.w*b.w;
#pragma unroll
  for (int off = 32; off; off >>= 1) {
    s += __shfl_xor(s, off);
    sq += __shfl_xor(sq, off);
  }
  const float mean = s * (1.f / 512.f);
  const float rstd = rsqrtf(sq * (1.f / 512.f) - mean * mean + 1e-5f);
  const int c = lane * 8;
  const float v[8] = {a.x, a.y, a.z, a.w, b.x, b.y, b.z, b.w};
  float o[8];
#pragma unroll
  for (int j = 0; j < 8; ++j)
    o[j] = (v[j] - mean) * rstd * gam[c + j] + bet[c + j];
  uint4 pk;
  pk.x = pack2(o[0], o[1]); pk.y = pack2(o[2], o[3]);
  pk.z = pack2(o[4], o[5]); pk.w = pack2(o[6], o[7]);
  *(uint4*)(out + (size_t)row * 512 + c) = pk;
}

// ====== attention block 0: local window +-8, 16 q per block (4 waves x 4 q) ======
__global__ __launch_bounds__(256)
void attn_local(const u16* __restrict__ qkv, u16* __restrict__ out) {
  const int q0 = blockIdx.x * 16;
  const int h = blockIdx.y, b = blockIdx.z;
  const int tid = threadIdx.x, lane = tid & 63, wave = tid >> 6;
  __shared__ float ksm[32][65];
  __shared__ float vsm[32][65];
  __shared__ float qsm[4][64];
  __shared__ float ssm[4][20];
  __shared__ float psm[4][20];
  const u16* base = qkv + (size_t)(b * 1024) * 1536;
#pragma unroll
  for (int it = 0; it < 2; ++it) {
    const int u = tid + it * 256;
    const int r = u >> 4, seg = u & 15;
    const int rg = q0 - 8 + r;
    if ((unsigned)rg < 1024u) {
      const uint4 v = *(const uint4*)(base + (size_t)rg * 1536 + 512 + h * 64 +
                                      (seg < 8 ? seg * 8 : 512 + (seg - 8) * 8));
      float* dstrow = (seg < 8) ? &ksm[r][(seg & 7) * 8] : &vsm[r][(seg & 7) * 8];
      dstrow[0] = bf2f((u16)(v.x & 0xffffu)); dstrow[1] = bf2f((u16)(v.x >> 16));
      dstrow[2] = bf2f((u16)(v.y & 0xffffu)); dstrow[3] = bf2f((u16)(v.y >> 16));
      dstrow[4] = bf2f((u16)(v.z & 0xffffu)); dstrow[5] = bf2f((u16)(v.z >> 16));
      dstrow[6] = bf2f((u16)(v.w & 0xffffu)); dstrow[7] = bf2f((u16)(v.w >> 16));
    }
  }
  __syncthreads();
#pragma unroll 1
  for (int i = 0; i < 4; ++i) {
    const int q = q0 + wave * 4 + i;
    qsm[wave][lane] = bf2f(base[(size_t)q * 1536 + h * 64 + lane]);
    __syncthreads();
    int lo = q - 8; if (lo < 0) lo = 0;
    int hi = q + 8; if (hi > 1023) hi = 1023;
    const int nk = hi - lo + 1;
    const int jb = lo - (q0 - 8);
    if (lane < nk) {
      float s = 0.f;
#pragma unroll
      for (int d = 0; d < 64; ++d) s = fmaf(qsm[wave][d], ksm[jb + lane][d], s);
      ssm[wave][lane] = s * 0.125f;
    }
    __syncthreads();
    float mx = -1e30f;
    for (int j = 0; j < nk; ++j) mx = fmaxf(mx, ssm[wave][j]);
    if (lane < nk) psm[wave][lane] = expf(ssm[wave][lane] - mx);
    __syncthreads();
    float l = 0.f, o = 0.f;
    for (int j = 0; j < nk; ++j) {
      const float p = psm[wave][j];
      l += p;
      o = fmaf(p, vsm[jb + j][lane], o);
    }
    out[(size_t)(b * 1024 + q) * 512 + h * 64 + lane] = f2bf(o / l);
    __syncthreads();
  }
}

// ===== attention block 1, fused: blocks <2048 copy v; blocks >=2048 full softmax ====
__global__ __launch_bounds__(256)
void attn_glob(const u16* __restrict__ qkv, u16* __restrict__ out) {
  __shared__ float qs[64];
  __shared__ float ps[1024];
  __shared__ float wred[8];
  __shared__ float osum[4][64];
  if (blockIdx.x < 2048) {
    const int i = blockIdx.x * 256 + threadIdx.x;
    const int row = i >> 6;
    const int col = (i & 63) * 8;
    const int q = row & 1023;
    if (q % 100 == 0) return;
    *(uint4*)(out + (size_t)row * 512 + col) =
        *(const uint4*)(qkv + (size_t)row * 1536 + 1024 + col);
    return;
  }
  const int l = blockIdx.x - 2048;
  const int q = (l % 11) * 100;
  const int h = (l / 11) & 7, b = l / 88;
  const int tid = threadIdx.x, lane = tid & 63, wave = tid >> 6;
  const u16* base = qkv + (size_t)(b * 1024) * 1536;
  if (tid < 64) qs[tid] = bf2f(base[(size_t)q * 1536 + h * 64 + tid]);
  __syncthreads();
  float sv[4];
  float mx = -1e30f;
#pragma unroll
  for (int i = 0; i < 4; ++i) {
    const int k = tid + i * 256;
    const u16* kr = base + (size_t)k * 1536 + 512 + h * 64;
    float s = 0.f;
#pragma unroll
    for (int seg = 0; seg < 8; ++seg)
      s += dot8(&qs[seg * 8], *(const uint4*)(kr + seg * 8));
    sv[i] = s * 0.125f;
    mx = fmaxf(mx, sv[i]);
  }
#pragma unroll
  for (int off = 32; off; off >>= 1) mx = fmaxf(mx, __shfl_xor(mx, off));
  if (lane == 0) wred[wave] = mx;
  __syncthreads();
  mx = fmaxf(fmaxf(wred[0], wred[1]), fmaxf(wred[2], wred[3]));
  float ls = 0.f;
#pragma unroll
  for (int i = 0; i < 4; ++i) {
    const float p = expf(sv[i] - mx);
    ps[tid + i * 256] = p;
    ls += p;
  }
#pragma unroll
  for (int off = 32; off; off >>= 1) ls += __shfl_xor(ls, off);
  if (lane == 0) wred[4 + wave] = ls;
  __syncthreads();
  const float lsum = wred[4] + wred[5] + wred[6] + wred[7];
  float o = 0.f;
  const u16* vb = base + 1024 + h * 64 + lane;
#pragma unroll 8
  for (int k = wave * 256; k < wave * 256 + 256; ++k)
    o = fmaf(ps[k], bf2f(vb[(size_t)k * 1536]), o);
  osum[wave][lane] = o;
  __syncthreads();
  if (wave == 0) {
    const float t = osum[0][lane] + osum[1][lane] + osum[2][lane] + osum[3][lane];
    out[(size_t)(b * 1024 + q) * 512 + h * 64 + lane] = f2bf(t / lsum);
  }
}

// ================= launch =================
extern "C" void kernel_launch(void* const* d_in, const int* in_sizes, int n_in,
                              void* d_out, int out_size, void* d_ws, size_t ws_size,
                              hipStream_t stream) {
  auto F = [&](int i) { return (const float*)d_in[i]; };
  const float* x = F(0);
  const float* proj_w = F(25); const float* proj_b = F(26);
  const float* w_in = F(27);  const float* b_in = F(28);
  const float* w_out = F(29); const float* b_out = F(30);
  const float* l1s = F(31); const float* l1b = F(32);
  const float* l2s = F(33); const float* l2b = F(34);
  const float* w1 = F(35); const float* b1 = F(36);
  const float* w2 = F(37); const float* b2 = F(38);

  char* wsb = (char*)d_ws;
  const size_t MB = 1024 * 1024;
  u16* projT = (u16*)(wsb + 0);
  u16* winT  = (u16*)(wsb + 1 * MB);
  u16* woutT = (u16*)(wsb + 4 * MB);
  u16* w1T   = (u16*)(wsb + 5 * MB);
  u16* w2T   = (u16*)(wsb + 9 * MB);
  u16* wp2   = (u16*)(wsb + 13 * MB);
  u16* zpad  = (u16*)(wsb + 13 * MB + 512 * 1024);  // 256B zero pad
  u16* wp3   = (u16*)(wsb + 14 * MB);
  u16* wp4   = (u16*)(wsb + 16 * MB);
  float* pe  = (float*)(wsb + 18 * MB);   // 1024x512 f32 = 2 MB
  char* bufA = wsb + 20 * MB;
  char* bufB = wsb + 68 * MB;
  float* h = (float*)d_out;

  u16* c1o = (u16*)bufA;
  u16* c2o = (u16*)bufB;
  u16* c3o = (u16*)bufA;
  u16* prA = (u16*)bufB;
  u16* xln = (u16*)bufB;
  u16* qkv = (u16*)(bufB + 9 * MB);
  u16* att = (u16*)bufA;
  u16* m1b = (u16*)(bufA + 9 * MB);

  // ---- fused weight prep + PE table + zpad (one launch) ----
  prep_all<<<13609, 256, 0, stream>>>(
      proj_w, w_in, w_out, w1, w2,
      F(7), F(9), F(12), F(13), F(15), F(18), F(19), F(21), F(24),
      projT, winT, woutT, w1T, w2T, wp2, wp3, wp4, pe, zpad);

  // ---- conv stack (NHWC bf16) ----
  conv1_k<<<dim3(4, 64, 8), 256, 0, stream>>>(x, F(1), F(2), F(3), F(4), F(5), F(6), c1o);
  conv_mfma<32, 64, 32, 64, 5, 2, 32, 2, 2, 0><<<dim3(256, 8), 256, 0, stream>>>(
      c1o, wp2, F(8), F(9), F(10), F(11), F(12), zpad, c2o);
  conv_mfma<64, 32, 16, 128, 7, 3, 64, 1, 4, 0><<<dim3(256, 8), 256, 0, stream>>>(
      c2o, wp3, F(14), F(15), F(16), F(17), F(18), zpad, c3o);
  conv_mfma<128, 16, 8, 128, 7, 3, 64, 1, 4, 1><<<dim3(128, 8), 256, 0, stream>>>(
      c3o, wp4, F(20), F(21), F(22), F(23), F(24), zpad, prA);

  // ---- proj + bias + posenc(table) -> h (f32), BK=128 (grid 256 = 1 block/CU) ----
  gemm_bf16<4, 128><<<256, 256, 0, stream>>>(prA, projT, proj_b, pe, h,
                                             8192, 512, 1024, 4);
  for (int i = 0; i < 2; ++i) {
    ln_k<<<2048, 256, 0, stream>>>(h, l1s + i * 512, l1b + i * 512, xln);
    gemm_bf16<0, 64><<<768, 256, 0, stream>>>(
        xln, winT + (size_t)i * 1536 * 512, b_in + i * 1536, nullptr, qkv,
        8192, 1536, 512, 12);
    if (i == 0) {
      attn_local<<<dim3(64, 8, 8), 256, 0, stream>>>(qkv, att);
    } else {
      attn_glob<<<2752, 256, 0, stream>>>(qkv, att);
    }
    gemm_bf16<3, 128><<<256, 256, 0, stream>>>(
        att, woutT + (size_t)i * 512 * 512, b_out + i * 512, h, h,
        8192, 512, 512, 4);
    ln_k<<<2048, 256, 0, stream>>>(h, l2s + i * 512, l2b + i * 512, xln);
    gemm_bf16<2, 64><<<1024, 256, 0, stream>>>(
        xln, w1T + (size_t)i * 2048 * 512, b1 + i * 2048, nullptr, m1b,
        8192, 2048, 512, 16);
    gemm_bf16<3, 128><<<256, 256, 0, stream>>>(
        m1b, w2T + (size_t)i * 512 * 2048, b2 + i * 512, h, h,
        8192, 512, 2048, 4);
  }
}